// Round 14
// baseline (1109.051 us; speedup 1.0000x reference)
//
#include <hip/hip_runtime.h>
#include <hip/hip_bf16.h>

typedef float f32x4 __attribute__((ext_vector_type(4)));
typedef __bf16 bf16x8 __attribute__((ext_vector_type(8)));
typedef unsigned short u16;

#define T_TOK 4096
#define DIMK 2048
#define INTERN 1024
#define NEXP 32
#define NTOPK 6
#define NGRP 8
#define NTOPG 4
#define SINTER 2048
#define MAXPADROWS 29184

__device__ __forceinline__ void glds16(const void* g, void* l) {
    auto* gp = (const __attribute__((address_space(1))) int*)(g);
    auto* lp = (__attribute__((address_space(3))) int*)(l);
    __builtin_amdgcn_global_load_lds(gp, lp, 16, 0, 0);
}

// Global chunked+swizzled layout (unchanged): row-chunks 128, k-chunks 64.
// In-chunk: off = row*64 + ((g ^ (row&7))<<3) + (k&7), g=(k>>3)&7.
__device__ __forceinline__ size_t toff(int row, int k, int K) {
    int g = (k >> 3) & 7;
    return (size_t)(row >> 7) * (size_t)(128 * K) + (size_t)(k >> 6) * 8192 +
           (size_t)((row & 127) * 64 + ((g ^ (row & 7)) << 3) + (k & 7));
}

// ---------------- cast x fp32 -> bf16 chunked ----------------
__global__ __launch_bounds__(256) void cast_x_tiled_kernel(const float* __restrict__ in, u16* __restrict__ out) {
    int gi = (blockIdx.x * 256 + threadIdx.x) * 8;
    int row = gi >> 11, k = gi & 2047;
    const float4* p = reinterpret_cast<const float4*>(in + gi);
    float4 a = p[0], b = p[1];
    bf16x8 v;
    v[0] = (__bf16)a.x; v[1] = (__bf16)a.y; v[2] = (__bf16)a.z; v[3] = (__bf16)a.w;
    v[4] = (__bf16)b.x; v[5] = (__bf16)b.y; v[6] = (__bf16)b.z; v[7] = (__bf16)b.w;
    *reinterpret_cast<bf16x8*>(out + toff(row, k, DIMK)) = v;
}

// ---------------- single transpose: fp32 [KD][JD] -> bf16 chunked [JD][KD] ----------------
template <int KD, int JD>
__global__ __launch_bounds__(256) void trans_tiled_kernel(const float* __restrict__ in, u16* __restrict__ out) {
    __shared__ float tile[64 * 65];
    const int t = threadIdx.x;
    const float* ib = in + (size_t)blockIdx.z * KD * JD;
    u16* ob = out + (size_t)blockIdx.z * KD * JD;
    const int j0 = blockIdx.x * 64, k0 = blockIdx.y * 64;
    {
        const int c4 = (t & 15) * 4;
#pragma unroll
        for (int i = 0; i < 4; ++i) {
            const int r = (t >> 4) + i * 16;
            float4 v = *reinterpret_cast<const float4*>(&ib[(size_t)(k0 + r) * JD + j0 + c4]);
            tile[r * 65 + c4 + 0] = v.x;
            tile[r * 65 + c4 + 1] = v.y;
            tile[r * 65 + c4 + 2] = v.z;
            tile[r * 65 + c4 + 3] = v.w;
        }
    }
    __syncthreads();
    {
        const int jl = t >> 2, kh = (t & 3) * 16;
        const int n = j0 + jl;
        bf16x8 v0, v1;
#pragma unroll
        for (int j = 0; j < 8; ++j) v0[j] = (__bf16)tile[(kh + j) * 65 + jl];
#pragma unroll
        for (int j = 0; j < 8; ++j) v1[j] = (__bf16)tile[(kh + 8 + j) * 65 + jl];
        *reinterpret_cast<bf16x8*>(ob + toff(n, k0 + kh, KD)) = v0;
        *reinterpret_cast<bf16x8*>(ob + toff(n, k0 + kh + 8, KD)) = v1;
    }
}

// ---------------- cat transpose: wg,wu [KD][JD] -> Wcat chunked [2*JD][KD] ----------------
template <int KD, int JD>
__global__ __launch_bounds__(256) void cat_trans_kernel(const float* __restrict__ g0, const float* __restrict__ u0,
                                                        u16* __restrict__ out) {
    __shared__ float tile[64 * 65];
    const int t = threadIdx.x;
    const size_t so = (size_t)blockIdx.z * KD * JD;
    u16* ob = out + (size_t)blockIdx.z * (2 * (size_t)KD * JD);
    const int j0 = blockIdx.x * 32, k0 = blockIdx.y * 64;
    const int kl = t >> 2, jf = (t & 3) * 4;
#pragma unroll
    for (int s = 0; s < 2; ++s) {
        const float* src = (s ? u0 : g0) + so;
#pragma unroll
        for (int rep = 0; rep < 2; ++rep) {
            int jb = jf + rep * 16;
            float4 v = *reinterpret_cast<const float4*>(&src[(size_t)(k0 + kl) * JD + j0 + jb]);
            int nl = ((jb >> 4) << 5) + s * 16 + (jb & 15);
            tile[kl * 65 + nl + 0] = v.x;
            tile[kl * 65 + nl + 1] = v.y;
            tile[kl * 65 + nl + 2] = v.z;
            tile[kl * 65 + nl + 3] = v.w;
        }
    }
    __syncthreads();
    {
        const int nl = t >> 2, kh = (t & 3) * 16;
        const int n = 2 * j0 + nl;
        bf16x8 v0, v1;
#pragma unroll
        for (int j = 0; j < 8; ++j) v0[j] = (__bf16)tile[(kh + j) * 65 + nl];
#pragma unroll
        for (int j = 0; j < 8; ++j) v1[j] = (__bf16)tile[(kh + 8 + j) * 65 + nl];
        *reinterpret_cast<bf16x8*>(ob + toff(n, k0 + kh, KD)) = v0;
        *reinterpret_cast<bf16x8*>(ob + toff(n, k0 + kh + 8, KD)) = v1;
    }
}

// ---------------- gate ----------------
__global__ __launch_bounds__(64) void gate_kernel(const float* __restrict__ x, const float* __restrict__ gw,
                                                  int* __restrict__ counts, int* __restrict__ ids,
                                                  int* __restrict__ tok2row, float* __restrict__ wtok) {
    const int t = blockIdx.x;
    const int lane = threadIdx.x;
    __shared__ float logits[NEXP];
    const float4* xr = reinterpret_cast<const float4*>(x + (size_t)t * DIMK);
    for (int e = 0; e < NEXP; ++e) {
        const float4* gr = reinterpret_cast<const float4*>(gw + (size_t)e * DIMK);
        float acc = 0.f;
#pragma unroll
        for (int i = 0; i < DIMK / 4 / 64; ++i) {
            float4 xv = xr[lane + i * 64];
            float4 gv = gr[lane + i * 64];
            acc += xv.x * gv.x + xv.y * gv.y + xv.z * gv.z + xv.w * gv.w;
        }
#pragma unroll
        for (int s = 32; s; s >>= 1) acc += __shfl_xor(acc, s);
        if (lane == 0) logits[e] = acc;
    }
    if (lane != 0) return;
    float sc[NEXP];
#pragma unroll
    for (int e = 0; e < NEXP; ++e) sc[e] = logits[e];
    float mx = sc[0];
#pragma unroll
    for (int e = 1; e < NEXP; ++e) mx = fmaxf(mx, sc[e]);
    float ssum = 0.f;
#pragma unroll
    for (int e = 0; e < NEXP; ++e) { sc[e] = __expf(sc[e] - mx); ssum += sc[e]; }
    const float inv = 1.f / ssum;
    float gsc[NGRP];
#pragma unroll
    for (int g = 0; g < NGRP; ++g) {
        float m2 = sc[g * 4];
#pragma unroll
        for (int j = 1; j < 4; ++j) m2 = fmaxf(m2, sc[g * 4 + j]);
        gsc[g] = m2;
    }
    int gsel = 0;
    for (int r = 0; r < NTOPG; ++r) {
        float bv = -1.f; int bi = 0;
#pragma unroll
        for (int g = 0; g < NGRP; ++g) {
            bool c = (((gsel >> g) & 1) == 0) && (gsc[g] > bv);
            bv = c ? gsc[g] : bv; bi = c ? g : bi;
        }
        gsel |= (1 << bi);
    }
    float msk[NEXP];
#pragma unroll
    for (int e = 0; e < NEXP; ++e) msk[e] = ((gsel >> (e >> 2)) & 1) ? sc[e] : -1.f;
    for (int r = 0; r < NTOPK; ++r) {
        float bv = -3.f; int bi = 0;
#pragma unroll
        for (int e = 0; e < NEXP; ++e) {
            bool c = msk[e] > bv;
            bv = c ? msk[e] : bv; bi = c ? e : bi;
        }
#pragma unroll
        for (int e = 0; e < NEXP; ++e) if (e == bi) msk[e] = -2.f;
        float w = bv * inv;
        int slot = atomicAdd(&counts[bi], 1);
        ids[bi * T_TOK + slot] = t;
        tok2row[t * NTOPK + r] = (bi << 12) | slot;
        wtok[t * NTOPK + r] = w;
    }
}

__global__ void scan_kernel(const int* __restrict__ counts, int* __restrict__ poff) {
    if (threadIdx.x == 0) {
        int o = 0;
        for (int e = 0; e < NEXP; ++e) { poff[e] = o; o += (counts[e] + 127) & ~127; }
    }
}

// ================= 256x128 / BK=32 / 8-wave (2M x 4N) / 1-barrier-per-tile / 2 blocks/CU =================
// LDS 56KB: A 2x16KB dbuf (dist-1), B 3x8KB ring (dist-2). Per tile:
//   dsrA(4)+dsrB(2); SA(t+1,2)+SB(t+2,1); 8 MFMA; dsrA(4); 8 MFMA; vmcnt(1|0); bar
// vmcnt(1) retires {A(t+1), B(t+1)} and keeps SB(t+2) in flight (2-tile B flight).
// BK=32 LDS swizzle: slot s = g ^ ((row>>1)&3) (4 granules) -> 2-way bank (free) on b128 reads.
// Source pre-swizzle per kt-parity maps the chunked-64 global layout into the linear DMA dest.

// GEMM1 fused: expert (z<32, gather-A from xbT via ids) + shared (z>=32).
__global__ __launch_bounds__(512, 4) void gemm1_fused_kernel(
    const u16* __restrict__ xbT, const u16* __restrict__ WcatE, u16* __restrict__ H,
    const u16* __restrict__ WcatS, u16* __restrict__ Hs,
    const int* __restrict__ counts, const int* __restrict__ poff, const int* __restrict__ ids) {
    __shared__ u16 Alds[2 * 8192];
    __shared__ u16 Blds[3 * 4096];
    constexpr int NT = DIMK / 32;  // 64

    int bm, bn, M, Mpad, hbase, HKdim, e = 0;
    const u16* b0;
    u16* ho;
    bool gath;
    if (blockIdx.z < 32) {
        int lin = blockIdx.x + 16 * (blockIdx.y + 16 * blockIdx.z);
        e = 31 - (((lin >> 11) << 3) | (lin & 7));
        int j = (lin >> 3) & 255;
        bm = j & 15; bn = j >> 4;                 // bn 0..15
        M = counts[e];
        if (bm * 256 >= M) return;
        Mpad = (M + 127) & ~127;
        hbase = poff[e];
        b0 = WcatE + (size_t)e * 2048 * DIMK;
        ho = H; HKdim = INTERN; gath = true;
    } else {
        int lin = blockIdx.x + 16 * (blockIdx.y + 16 * (blockIdx.z - 32));  // 0..511
        int swz = (lin & 7) * 64 + (lin >> 3);
        bm = swz & 15; bn = swz >> 4;             // bn 0..31
        M = T_TOK; Mpad = T_TOK; hbase = 0;
        b0 = WcatS; ho = Hs; HKdim = SINTER; gath = false;
    }

    const int tid = threadIdx.x;
    const int sdr = tid >> 2, ss = tid & 3;       // stage row / slot
    // A sources: j sub-block (rows 0-127 / 128-255), parity p of kt
    size_t srcA[2][2];
#pragma unroll
    for (int j = 0; j < 2; ++j) {
        int drow = j * 128 + sdr;
        int arow = bm * 256 + drow;
        int tok;
        if (gath) { int cr = arow < M ? arow : M - 1; tok = ids[e * T_TOK + cr]; }
        else tok = arow;
        int g = ss ^ ((drow >> 1) & 3);
#pragma unroll
        for (int p = 0; p < 2; ++p) {
            int gg = p * 4 + g;
            srcA[j][p] = (size_t)(tok >> 7) * (size_t)(128 * 2048) + (size_t)((tok & 127) * 64 + ((gg ^ (tok & 7)) << 3));
        }
    }
    // B sources
    const u16* bCh = b0 + (size_t)bn * (128 * DIMK);
    int srcB[2];
    {
        int g = ss ^ ((sdr >> 1) & 3);
#pragma unroll
        for (int p = 0; p < 2; ++p) {
            int gg = p * 4 + g;
            srcB[p] = sdr * 64 + ((gg ^ (sdr & 7)) << 3);
        }
    }

    const int lane = tid & 63, wv = tid >> 6;
    const int wr = wv >> 2, wc = wv & 3;
    const int l15 = lane & 15, lk = lane >> 4;

    f32x4 acc[8][2];
#pragma unroll
    for (int m = 0; m < 8; ++m)
#pragma unroll
        for (int n = 0; n < 2; ++n) acc[m][n] = {0.f, 0.f, 0.f, 0.f};

    auto SA = [&](int kt, int buf) {
        const size_t cko = (size_t)(kt >> 1) * 8192;
        const int p = kt & 1;
        glds16(xbT + cko + srcA[0][p], &Alds[buf * 8192 + tid * 8]);
        glds16(xbT + cko + srcA[1][p], &Alds[buf * 8192 + 4096 + tid * 8]);
    };
    auto SB = [&](int kt, int buf) {
        glds16(bCh + (size_t)(kt >> 1) * 8192 + srcB[kt & 1], &Blds[buf * 4096 + tid * 8]);
    };
    bf16x8 afr[4], bfr[2];
    auto DSRA = [&](int buf, int mb) {
#pragma unroll
        for (int mi = 0; mi < 4; ++mi) {
            int rl = wr * 128 + (mb * 4 + mi) * 16 + l15;
            afr[mi] = *reinterpret_cast<const bf16x8*>(
                &Alds[buf * 8192 + rl * 32 + ((lk ^ ((rl >> 1) & 3)) << 3)]);
        }
    };
    auto DSRB = [&](int buf) {
#pragma unroll
        for (int nj = 0; nj < 2; ++nj) {
            int rc = wc * 32 + nj * 16 + l15;
            bfr[nj] = *reinterpret_cast<const bf16x8*>(
                &Blds[buf * 4096 + rc * 32 + ((lk ^ ((rc >> 1) & 3)) << 3)]);
        }
    };

    // prologue: A(0), B(0), B(1). vmcnt(1) leaves SB(1) in flight, tile 0 complete.
    SA(0, 0); SB(0, 0); SB(1, 1);
    asm volatile("s_waitcnt vmcnt(1)" ::: "memory");
    __builtin_amdgcn_s_barrier();

#pragma unroll 1
    for (int t = 0; t < NT; ++t) {
        const int abuf = t & 1;
        const int bbuf = t % 3;
        DSRA(abuf, 0);
        DSRB(bbuf);
        if (t + 1 < NT) SA(t + 1, abuf ^ 1);
        if (t + 2 < NT) SB(t + 2, (t + 2) % 3);
        __builtin_amdgcn_s_setprio(1);
#pragma unroll
        for (int mi = 0; mi < 4; ++mi)
#pragma unroll
            for (int nj = 0; nj < 2; ++nj)
                acc[mi][nj] = __builtin_amdgcn_mfma_f32_16x16x32_bf16(afr[mi], bfr[nj], acc[mi][nj], 0, 0, 0);
        __builtin_amdgcn_s_setprio(0);
        DSRA(abuf, 1);
        __builtin_amdgcn_s_setprio(1);
#pragma unroll
        for (int mi = 0; mi < 4; ++mi)
#pragma unroll
            for (int nj = 0; nj < 2; ++nj)
                acc[4 + mi][nj] = __builtin_amdgcn_mfma_f32_16x16x32_bf16(afr[mi], bfr[nj], acc[4 + mi][nj], 0, 0, 0);
        __builtin_amdgcn_s_setprio(0);
        if (t + 2 < NT) { asm volatile("s_waitcnt vmcnt(1)" ::: "memory"); }
        else { asm volatile("s_waitcnt vmcnt(0)" ::: "memory"); }
        __builtin_amdgcn_s_barrier();
    }

    // epilogue: h = silu(g)*u -> H chunked. Wave outputs 128 rows x 16 H cols.
#pragma unroll
    for (int mI = 0; mI < 8; ++mI) {
#pragma unroll
        for (int r = 0; r < 4; ++r) {
            int grow = bm * 256 + wr * 128 + mI * 16 + lk * 4 + r;
            if (grow < Mpad) {
                float gg = acc[mI][0][r];
                float uu = acc[mI][1][r];
                float h = gg / (1.f + __expf(-gg)) * uu;
                int jcol = (bn * 4 + wc) * 16 + l15;
                __bf16 hb = (__bf16)h;
                ho[toff(hbase + grow, jcol, HKdim)] = __builtin_bit_cast(u16, hb);
            }
        }
    }
}

// GEMM2 fused: expert (z<32) -> Ye rows; shared (z>=32) K-split -> Yss slices.
__global__ __launch_bounds__(512, 4) void gemm2_fused_kernel(
    const u16* __restrict__ H, const u16* __restrict__ wdT, u16* __restrict__ Ye,
    const u16* __restrict__ Hs, const u16* __restrict__ swdT, u16* __restrict__ Yss,
    const int* __restrict__ counts, const int* __restrict__ poff) {
    __shared__ u16 Alds[2 * 8192];
    __shared__ u16 Blds[3 * 4096];
    constexpr int NT = 32;

    int bm, bn, M, rowbase, AKK, ck0;
    const u16 *aBase, *bBase;
    u16* yo;
    if (blockIdx.z < 32) {
        int lin = blockIdx.x + 16 * (blockIdx.y + 16 * blockIdx.z);
        int e = 31 - (((lin >> 11) << 3) | (lin & 7));
        int j = (lin >> 3) & 255;
        bm = j & 15; bn = j >> 4;
        M = counts[e];
        if (bm * 256 >= M) return;
        rowbase = poff[e];
        aBase = H + (size_t)poff[e] * INTERN;
        bBase = wdT + (size_t)e * 2048 * INTERN;
        yo = Ye; AKK = INTERN; ck0 = 0;
    } else {
        int lin = blockIdx.x + 16 * (blockIdx.y + 16 * (blockIdx.z - 32));  // 0..511
        int swz = (lin & 7) * 64 + (lin >> 3);
        bm = swz & 15; bn = (swz >> 4) & 15;
        int ks = swz >> 8;
        M = T_TOK; rowbase = ks * T_TOK;
        aBase = Hs; bBase = swdT; yo = Yss; AKK = SINTER; ck0 = ks * 16;
    }
    const int tid = threadIdx.x;
    const int sdr = tid >> 2, ss = tid & 3;
    size_t srcA[2][2];
#pragma unroll
    for (int j = 0; j < 2; ++j) {
        int lrow = bm * 256 + j * 128 + sdr;
        int cr = (rowbase == 0 || true) ? lrow : lrow;  // local row within padded segment
        int g = ss ^ (((j * 128 + sdr) >> 1) & 3);
#pragma unroll
        for (int p = 0; p < 2; ++p) {
            int gg = p * 4 + g;
            srcA[j][p] = (size_t)(cr >> 7) * (size_t)(128 * AKK) + (size_t)((cr & 127) * 64 + ((gg ^ (cr & 7)) << 3));
        }
    }
    const u16* bCh = bBase + (size_t)bn * (128 * AKK);
    int srcB[2];
    {
        int g = ss ^ ((sdr >> 1) & 3);
#pragma unroll
        for (int p = 0; p < 2; ++p) {
            int gg = p * 4 + g;
            srcB[p] = sdr * 64 + ((gg ^ (sdr & 7)) << 3);
        }
    }
    const size_t ckBase = (size_t)ck0 * 8192;

    const int lane = tid & 63, wv = tid >> 6;
    const int wr = wv >> 2, wc = wv & 3;
    const int l15 = lane & 15, lk = lane >> 4;

    f32x4 acc[8][2];
#pragma unroll
    for (int m = 0; m < 8; ++m)
#pragma unroll
        for (int n = 0; n < 2; ++n) acc[m][n] = {0.f, 0.f, 0.f, 0.f};

    auto SA = [&](int kt, int buf) {
        const size_t cko = ckBase + (size_t)(kt >> 1) * 8192;
        const int p = kt & 1;
        glds16(aBase + cko + srcA[0][p], &Alds[buf * 8192 + tid * 8]);
        glds16(aBase + cko + srcA[1][p], &Alds[buf * 8192 + 4096 + tid * 8]);
    };
    auto SB = [&](int kt, int buf) {
        glds16(bCh + ckBase + (size_t)(kt >> 1) * 8192 + srcB[kt & 1], &Blds[buf * 4096 + tid * 8]);
    };
    bf16x8 afr[4], bfr[2];
    auto DSRA = [&](int buf, int mb) {
#pragma unroll
        for (int mi = 0; mi < 4; ++mi) {
            int rl = wr * 128 + (mb * 4 + mi) * 16 + l15;
            afr[mi] = *reinterpret_cast<const bf16x8*>(
                &Alds[buf * 8192 + rl * 32 + ((lk ^ ((rl >> 1) & 3)) << 3)]);
        }
    };
    auto DSRB = [&](int buf) {
#pragma unroll
        for (int nj = 0; nj < 2; ++nj) {
            int rc = wc * 32 + nj * 16 + l15;
            bfr[nj] = *reinterpret_cast<const bf16x8*>(
                &Blds[buf * 4096 + rc * 32 + ((lk ^ ((rc >> 1) & 3)) << 3)]);
        }
    };

    SA(0, 0); SB(0, 0); SB(1, 1);
    asm volatile("s_waitcnt vmcnt(1)" ::: "memory");
    __builtin_amdgcn_s_barrier();

#pragma unroll 1
    for (int t = 0; t < NT; ++t) {
        const int abuf = t & 1;
        const int bbuf = t % 3;
        DSRA(abuf, 0);
        DSRB(bbuf);
        if (t + 1 < NT) SA(t + 1, abuf ^ 1);
        if (t + 2 < NT) SB(t + 2, (t + 2) % 3);
        __builtin_amdgcn_s_setprio(1);
#pragma unroll
        for (int mi = 0; mi < 4; ++mi)
#pragma unroll
            for (int nj = 0; nj < 2; ++nj)
                acc[mi][nj] = __builtin_amdgcn_mfma_f32_16x16x32_bf16(afr[mi], bfr[nj], acc[mi][nj], 0, 0, 0);
        __builtin_amdgcn_s_setprio(0);
        DSRA(abuf, 1);
        __builtin_amdgcn_s_setprio(1);
#pragma unroll
        for (int mi = 0; mi < 4; ++mi)
#pragma unroll
            for (int nj = 0; nj < 2; ++nj)
                acc[4 + mi][nj] = __builtin_amdgcn_mfma_f32_16x16x32_bf16(afr[mi], bfr[nj], acc[4 + mi][nj], 0, 0, 0);
        __builtin_amdgcn_s_setprio(0);
        if (t + 2 < NT) { asm volatile("s_waitcnt vmcnt(1)" ::: "memory"); }
        else { asm volatile("s_waitcnt vmcnt(0)" ::: "memory"); }
        __builtin_amdgcn_s_barrier();
    }

#pragma unroll
    for (int mI = 0; mI < 8; ++mI) {
#pragma unroll
        for (int r = 0; r < 4; ++r) {
            int grow = bm * 256 + wr * 128 + mI * 16 + lk * 4 + r;
            if (grow < M) {
                u16* yr = yo + (size_t)(rowbase + grow) * 2048;
#pragma unroll
                for (int nj = 0; nj < 2; ++nj) {
                    int col = bn * 128 + wc * 32 + nj * 16 + l15;
                    __bf16 yb = (__bf16)acc[mI][nj][r];
                    yr[col] = __builtin_bit_cast(u16, yb);
                }
            }
        }
    }
}

// ---------------- combine: out[t] = Yss0[t] + Yss1[t] + sum_r w_r * Ye[row_r] ----------------
__global__ __launch_bounds__(256) void combine_kernel(const u16* __restrict__ Yss, const u16* __restrict__ Ye,
                                                      const int* __restrict__ tok2row, const float* __restrict__ wtok,
                                                      const int* __restrict__ poff, float* __restrict__ out) {
    const int t = blockIdx.x;
    const int c = threadIdx.x * 8;
    bf16x8 v0 = *reinterpret_cast<const bf16x8*>(Yss + (size_t)t * 2048 + c);
    bf16x8 v1 = *reinterpret_cast<const bf16x8*>(Yss + (size_t)(T_TOK + t) * 2048 + c);
    float acc[8];
#pragma unroll
    for (int j = 0; j < 8; ++j) acc[j] = (float)v0[j] + (float)v1[j];
#pragma unroll
    for (int r = 0; r < NTOPK; ++r) {
        int pk = tok2row[t * NTOPK + r];
        int e = pk >> 12, sl = pk & 4095;
        int row = poff[e] + sl;
        float w = wtok[t * NTOPK + r];
        bf16x8 v = *reinterpret_cast<const bf16x8*>(Ye + (size_t)row * 2048 + c);
#pragma unroll
        for (int j = 0; j < 8; ++j) acc[j] += w * (float)v[j];
    }
    float4 o0 = {acc[0], acc[1], acc[2], acc[3]};
    float4 o1 = {acc[4], acc[5], acc[6], acc[7]};
    float4* po = reinterpret_cast<float4*>(out + (size_t)t * 2048 + c);
    po[0] = o0; po[1] = o1;
}

extern "C" void kernel_launch(void* const* d_in, const int* in_sizes, int n_in,
                              void* d_out, int out_size, void* d_ws, size_t ws_size,
                              hipStream_t stream) {
    const float* x = (const float*)d_in[0];
    const float* gate_w = (const float*)d_in[1];
    const float* wg = (const float*)d_in[2];
    const float* wu = (const float*)d_in[3];
    const float* wd = (const float*)d_in[4];
    const float* swg = (const float*)d_in[5];
    const float* swu = (const float*)d_in[6];
    const float* swd = (const float*)d_in[7];
    float* out = (float*)d_out;

    char* ws = (char*)d_ws;
    size_t off = 0;
    auto alloc = [&](size_t bytes) {
        void* p = ws + off;
        off = (off + bytes + 255) & ~(size_t)255;
        return p;
    };
    u16* xbT = (u16*)alloc((size_t)T_TOK * DIMK * 2);                  // 16.8 MB
    u16* H = (u16*)alloc((size_t)MAXPADROWS * INTERN * 2);             // 59.8 MB
    u16* Hs = (u16*)alloc((size_t)T_TOK * SINTER * 2);                 // 16.8 MB
    u16* Ye = (u16*)alloc((size_t)MAXPADROWS * 2048 * 2);              // 119.6 MB
    u16* Yss = (u16*)alloc((size_t)2 * T_TOK * 2048 * 2);              // 33.6 MB
    int* ids = (int*)alloc((size_t)NEXP * T_TOK * 4);
    int* tok2row = (int*)alloc((size_t)T_TOK * NTOPK * 4);
    float* wtok = (float*)alloc((size_t)T_TOK * NTOPK * 4);
    int* counts = (int*)alloc(NEXP * 4);
    int* poff = (int*)alloc(NEXP * 4);
    u16* WcatS = (u16*)alloc((size_t)(2 * SINTER) * DIMK * 2);         // 16.8 MB
    u16* swdT = (u16*)alloc((size_t)DIMK * SINTER * 2);                // 8.4 MB
    u16* WcatE = (u16*)alloc((size_t)NEXP * (2 * INTERN) * DIMK * 2);  // 268.4 MB
    u16* wdT = WcatE;  // alias: wd transpose runs after GEMM1 consumed WcatE (stream-ordered)

    hipMemsetAsync(counts, 0, NEXP * 4, stream);
    cast_x_tiled_kernel<<<(T_TOK * DIMK) / (256 * 8), 256, 0, stream>>>(x, xbT);
    gate_kernel<<<T_TOK, 64, 0, stream>>>(x, gate_w, counts, ids, tok2row, wtok);
    scan_kernel<<<1, 64, 0, stream>>>(counts, poff);

    // weight reshapes
    cat_trans_kernel<DIMK, SINTER><<<dim3(SINTER / 32, DIMK / 64, 1), 256, 0, stream>>>(swg, swu, WcatS);
    cat_trans_kernel<DIMK, INTERN><<<dim3(INTERN / 32, DIMK / 64, NEXP), 256, 0, stream>>>(wg, wu, WcatE);
    trans_tiled_kernel<SINTER, DIMK><<<dim3(DIMK / 64, SINTER / 64, 1), 256, 0, stream>>>(swd, swdT);

    // fused GEMM1 (256x128/BK=32, 2 blocks/CU)
    gemm1_fused_kernel<<<dim3(16, 16, 34), 512, 0, stream>>>(
        xbT, WcatE, H, WcatS, Hs, counts, poff, ids);

    // wd transpose into aliased WcatE region (GEMM1 done by stream order)
    trans_tiled_kernel<INTERN, DIMK><<<dim3(DIMK / 64, INTERN / 64, NEXP), 256, 0, stream>>>(wd, wdT);

    // fused GEMM2 (256x128/BK=32, 2 blocks/CU): expert -> Ye; shared K-split -> Yss
    gemm2_fused_kernel<<<dim3(16, 16, 34), 512, 0, stream>>>(
        H, wdT, Ye, Hs, swdT, Yss, counts, poff);

    // final combine -> out
    combine_kernel<<<T_TOK, 256, 0, stream>>>(Yss, Ye, tok2row, wtok, poff, out);
}

// Round 15
// 1013.564 us; speedup vs baseline: 1.0942x; 1.0942x over previous
//
#include <hip/hip_runtime.h>
#include <hip/hip_bf16.h>

typedef float f32x4 __attribute__((ext_vector_type(4)));
typedef __bf16 bf16x8 __attribute__((ext_vector_type(8)));
typedef unsigned short u16;

#define T_TOK 4096
#define DIMK 2048
#define INTERN 1024
#define NEXP 32
#define NTOPK 6
#define NGRP 8
#define NTOPG 4
#define SINTER 2048
#define MAXPADROWS 29184

__device__ __forceinline__ void glds16(const void* g, void* l) {
    auto* gp = (const __attribute__((address_space(1))) int*)(g);
    auto* lp = (__attribute__((address_space(3))) int*)(l);
    __builtin_amdgcn_global_load_lds(gp, lp, 16, 0, 0);
}

// Chunked+swizzled layout for [Rows][K] bf16: row-chunks 128, k-chunks 64.
// In-chunk (16KB=8192 elems): off = row*64 + ((g ^ (row&7))<<3) + (k&7), g=(k>>3)&7.
__device__ __forceinline__ size_t toff(int row, int k, int K) {
    int g = (k >> 3) & 7;
    return (size_t)(row >> 7) * (size_t)(128 * K) + (size_t)(k >> 6) * 8192 +
           (size_t)((row & 127) * 64 + ((g ^ (row & 7)) << 3) + (k & 7));
}

// ---------------- cast x fp32 -> bf16 chunked ----------------
__global__ __launch_bounds__(256) void cast_x_tiled_kernel(const float* __restrict__ in, u16* __restrict__ out) {
    int gi = (blockIdx.x * 256 + threadIdx.x) * 8;
    int row = gi >> 11, k = gi & 2047;
    const float4* p = reinterpret_cast<const float4*>(in + gi);
    float4 a = p[0], b = p[1];
    bf16x8 v;
    v[0] = (__bf16)a.x; v[1] = (__bf16)a.y; v[2] = (__bf16)a.z; v[3] = (__bf16)a.w;
    v[4] = (__bf16)b.x; v[5] = (__bf16)b.y; v[6] = (__bf16)b.z; v[7] = (__bf16)b.w;
    *reinterpret_cast<bf16x8*>(out + toff(row, k, DIMK)) = v;
}

// ---------------- strip transpose: fp32 [KD][JD] -> bf16 chunked [JD][KD] ----------------
// Block owns a 64-row k-strip; loops j-tiles so each source row is consumed sequentially
// (page-friendly reads). JSPLIT splits the j-range for grid parallelism.
template <int KD, int JD, int JSPLIT>
__global__ __launch_bounds__(256) void trans_strip_kernel(const float* __restrict__ in, u16* __restrict__ out) {
    __shared__ float tile[64 * 65];
    const int t = threadIdx.x;
    const float* ib = in + (size_t)blockIdx.z * KD * JD;
    u16* ob = out + (size_t)blockIdx.z * KD * JD;
    const int k0 = blockIdx.x * 64;
    const int jbase = blockIdx.y * (JD / JSPLIT);
    const int c4 = (t & 15) * 4;
    const int jl = t >> 2, kh = (t & 3) * 16;
#pragma unroll 1
    for (int jt = 0; jt < JD / JSPLIT / 64; ++jt) {
        const int j0 = jbase + jt * 64;
#pragma unroll
        for (int i = 0; i < 4; ++i) {
            const int r = (t >> 4) + i * 16;
            float4 v = *reinterpret_cast<const float4*>(&ib[(size_t)(k0 + r) * JD + j0 + c4]);
            tile[r * 65 + c4 + 0] = v.x;
            tile[r * 65 + c4 + 1] = v.y;
            tile[r * 65 + c4 + 2] = v.z;
            tile[r * 65 + c4 + 3] = v.w;
        }
        __syncthreads();
        {
            const int n = j0 + jl;
            bf16x8 v0, v1;
#pragma unroll
            for (int j = 0; j < 8; ++j) v0[j] = (__bf16)tile[(kh + j) * 65 + jl];
#pragma unroll
            for (int j = 0; j < 8; ++j) v1[j] = (__bf16)tile[(kh + 8 + j) * 65 + jl];
            *reinterpret_cast<bf16x8*>(ob + toff(n, k0 + kh, KD)) = v0;
            *reinterpret_cast<bf16x8*>(ob + toff(n, k0 + kh + 8, KD)) = v1;
        }
        __syncthreads();
    }
}

// ---------------- strip cat transpose: wg,wu [KD][JD] -> Wcat chunked [2*JD][KD] ----------------
// Wcat row n <-> (s, j): n = ((j>>4)<<5) + s*16 + (j&15).
template <int KD, int JD, int JSPLIT>
__global__ __launch_bounds__(256) void cat_trans_strip_kernel(const float* __restrict__ g0, const float* __restrict__ u0,
                                                              u16* __restrict__ out) {
    __shared__ float tile[64 * 65];
    const int t = threadIdx.x;
    const int s = blockIdx.y / JSPLIT;
    const int jy = blockIdx.y % JSPLIT;
    const float* src = (s ? u0 : g0) + (size_t)blockIdx.z * KD * JD;
    u16* ob = out + (size_t)blockIdx.z * (2 * (size_t)KD * JD);
    const int k0 = blockIdx.x * 64;
    const int jbase = jy * (JD / JSPLIT);
    const int c4 = (t & 15) * 4;
    const int jl = t >> 2, kh = (t & 3) * 16;
#pragma unroll 1
    for (int jt = 0; jt < JD / JSPLIT / 64; ++jt) {
        const int j0 = jbase + jt * 64;
#pragma unroll
        for (int i = 0; i < 4; ++i) {
            const int r = (t >> 4) + i * 16;
            float4 v = *reinterpret_cast<const float4*>(&src[(size_t)(k0 + r) * JD + j0 + c4]);
            tile[r * 65 + c4 + 0] = v.x;
            tile[r * 65 + c4 + 1] = v.y;
            tile[r * 65 + c4 + 2] = v.z;
            tile[r * 65 + c4 + 3] = v.w;
        }
        __syncthreads();
        {
            const int j = j0 + jl;
            const int n = ((j >> 4) << 5) + s * 16 + (j & 15);
            bf16x8 v0, v1;
#pragma unroll
            for (int jj = 0; jj < 8; ++jj) v0[jj] = (__bf16)tile[(kh + jj) * 65 + jl];
#pragma unroll
            for (int jj = 0; jj < 8; ++jj) v1[jj] = (__bf16)tile[(kh + 8 + jj) * 65 + jl];
            *reinterpret_cast<bf16x8*>(ob + toff(n, k0 + kh, KD)) = v0;
            *reinterpret_cast<bf16x8*>(ob + toff(n, k0 + kh + 8, KD)) = v1;
        }
        __syncthreads();
    }
}

// ---------------- gate ----------------
__global__ __launch_bounds__(64) void gate_kernel(const float* __restrict__ x, const float* __restrict__ gw,
                                                  int* __restrict__ counts, int* __restrict__ ids,
                                                  int* __restrict__ tok2row, float* __restrict__ wtok) {
    const int t = blockIdx.x;
    const int lane = threadIdx.x;
    __shared__ float logits[NEXP];
    const float4* xr = reinterpret_cast<const float4*>(x + (size_t)t * DIMK);
    for (int e = 0; e < NEXP; ++e) {
        const float4* gr = reinterpret_cast<const float4*>(gw + (size_t)e * DIMK);
        float acc = 0.f;
#pragma unroll
        for (int i = 0; i < DIMK / 4 / 64; ++i) {
            float4 xv = xr[lane + i * 64];
            float4 gv = gr[lane + i * 64];
            acc += xv.x * gv.x + xv.y * gv.y + xv.z * gv.z + xv.w * gv.w;
        }
#pragma unroll
        for (int s = 32; s; s >>= 1) acc += __shfl_xor(acc, s);
        if (lane == 0) logits[e] = acc;
    }
    if (lane != 0) return;
    float sc[NEXP];
#pragma unroll
    for (int e = 0; e < NEXP; ++e) sc[e] = logits[e];
    float mx = sc[0];
#pragma unroll
    for (int e = 1; e < NEXP; ++e) mx = fmaxf(mx, sc[e]);
    float ssum = 0.f;
#pragma unroll
    for (int e = 0; e < NEXP; ++e) { sc[e] = __expf(sc[e] - mx); ssum += sc[e]; }
    const float inv = 1.f / ssum;
    float gsc[NGRP];
#pragma unroll
    for (int g = 0; g < NGRP; ++g) {
        float m2 = sc[g * 4];
#pragma unroll
        for (int j = 1; j < 4; ++j) m2 = fmaxf(m2, sc[g * 4 + j]);
        gsc[g] = m2;
    }
    int gsel = 0;
    for (int r = 0; r < NTOPG; ++r) {
        float bv = -1.f; int bi = 0;
#pragma unroll
        for (int g = 0; g < NGRP; ++g) {
            bool c = (((gsel >> g) & 1) == 0) && (gsc[g] > bv);
            bv = c ? gsc[g] : bv; bi = c ? g : bi;
        }
        gsel |= (1 << bi);
    }
    float msk[NEXP];
#pragma unroll
    for (int e = 0; e < NEXP; ++e) msk[e] = ((gsel >> (e >> 2)) & 1) ? sc[e] : -1.f;
    for (int r = 0; r < NTOPK; ++r) {
        float bv = -3.f; int bi = 0;
#pragma unroll
        for (int e = 0; e < NEXP; ++e) {
            bool c = msk[e] > bv;
            bv = c ? msk[e] : bv; bi = c ? e : bi;
        }
#pragma unroll
        for (int e = 0; e < NEXP; ++e) if (e == bi) msk[e] = -2.f;
        float w = bv * inv;
        int slot = atomicAdd(&counts[bi], 1);
        ids[bi * T_TOK + slot] = t;
        tok2row[t * NTOPK + r] = (bi << 12) | slot;
        wtok[t * NTOPK + r] = w;
    }
}

__global__ void scan_kernel(const int* __restrict__ counts, int* __restrict__ poff) {
    if (threadIdx.x == 0) {
        int o = 0;
        for (int e = 0; e < NEXP; ++e) { poff[e] = o; o += (counts[e] + 127) & ~127; }
    }
}

// ================= 256x256 / BK=64 / 8-wave (2M x 4N) / asymmetric-depth 8-phase core (r13) =================
// A: 2-buf, staged t+1 at ph0 (L3-warm). B: 3-buf, staged t+2 at ph1/ph2 (cold HBM, long flight).
// vmcnt(4) per tile leaves only SB(t+2)'s 4 loads in flight.

// GEMM1 fused: expert (z<32, gather-A from xbT via ids) + shared (z>=32).
__global__ __launch_bounds__(512, 2) void gemm1_fused_kernel(
    const u16* __restrict__ xbT, const u16* __restrict__ WcatE, u16* __restrict__ H,
    const u16* __restrict__ WcatS, u16* __restrict__ Hs,
    const int* __restrict__ counts, const int* __restrict__ poff, const int* __restrict__ ids) {
    __shared__ u16 Alds[2 * 16384];
    __shared__ u16 Blds[3 * 16384];
    constexpr int NT = DIMK / 64;  // 32

    int bm, bn, M, Mpad, hbase, HKdim, e = 0;
    const u16* b0;
    u16* ho;
    bool gath;
    if (blockIdx.z < 32) {
        int lin = blockIdx.x + 16 * (blockIdx.y + 8 * blockIdx.z);
        e = 31 - (((lin >> 10) << 3) | (lin & 7));
        int j = (lin >> 3) & 127;
        bm = j & 15; bn = j >> 4;
        M = counts[e];
        if (bm * 256 >= M) return;
        Mpad = (M + 127) & ~127;
        hbase = poff[e];
        b0 = WcatE + (size_t)e * 2048 * DIMK;
        ho = H; HKdim = INTERN; gath = true;
    } else {
        int lin = blockIdx.x + 16 * (blockIdx.y + 8 * (blockIdx.z - 32));
        int swz = (lin & 7) * 32 + (lin >> 3);
        bm = swz & 15; bn = swz >> 4;
        M = T_TOK; Mpad = T_TOK; hbase = 0;
        b0 = WcatS; ho = Hs; HKdim = SINTER; gath = false;
    }

    const int tid = threadIdx.x;
    const int t8 = tid * 8;
    size_t aSrc[2][2];
#pragma unroll
    for (int h = 0; h < 2; ++h)
#pragma unroll
        for (int j = 0; j < 2; ++j) {
            int drow = j * 64 + (tid >> 3);
            int row = bm * 256 + h * 128 + drow;
            int tok;
            if (gath) { int cr = row < M ? row : M - 1; tok = ids[e * T_TOK + cr]; }
            else tok = row;
            int slot = (tid & 7) ^ (drow & 7) ^ (tok & 7);
            aSrc[h][j] = (size_t)(tok >> 7) * (size_t)(128 * 2048) + (size_t)((tok & 127) * 64 + slot * 8);
        }
    const u16* bCh[2] = { b0 + (size_t)(2 * bn + 0) * (128 * 2048), b0 + (size_t)(2 * bn + 1) * (128 * 2048) };

    const int lane = tid & 63, wv = tid >> 6;
    const int wr = wv >> 2, wc = wv & 3;
    const int l15 = lane & 15, lk = lane >> 4;

    f32x4 acc[8][4];
#pragma unroll
    for (int m = 0; m < 8; ++m)
#pragma unroll
        for (int n = 0; n < 4; ++n) acc[m][n] = {0.f, 0.f, 0.f, 0.f};

    auto SA = [&](int kt, int h, int buf) {
        glds16(xbT + aSrc[h][0] + (size_t)kt * 8192, &Alds[buf * 16384 + h * 8192 + t8]);
        glds16(xbT + aSrc[h][1] + (size_t)kt * 8192, &Alds[buf * 16384 + h * 8192 + 4096 + t8]);
    };
    auto SB = [&](int kt, int h, int buf) {
        glds16(bCh[h] + (size_t)kt * 8192 + t8, &Blds[buf * 16384 + h * 8192 + t8]);
        glds16(bCh[h] + (size_t)kt * 8192 + 4096 + t8, &Blds[buf * 16384 + h * 8192 + 4096 + t8]);
    };
    bf16x8 afr[4][2], bfr0[2][2], bfr1[2][2];
    auto DSRA = [&](int buf, int mh) {
#pragma unroll
        for (int mi = 0; mi < 4; ++mi)
#pragma unroll
            for (int ki = 0; ki < 2; ++ki) {
                int rl = wr * 128 + mh * 64 + mi * 16 + l15;
                int g = ki * 4 + lk;
                afr[mi][ki] = *reinterpret_cast<const bf16x8*>(
                    &Alds[buf * 16384 + (rl >> 7) * 8192 + (rl & 127) * 64 + ((g ^ (rl & 7)) << 3)]);
            }
    };
    auto DSRB = [&](int buf, int nh, bf16x8 (&bf)[2][2]) {
#pragma unroll
        for (int nj = 0; nj < 2; ++nj)
#pragma unroll
            for (int ki = 0; ki < 2; ++ki) {
                int rc = wc * 64 + (nh * 2 + nj) * 16 + l15;
                int g = ki * 4 + lk;
                bf[nj][ki] = *reinterpret_cast<const bf16x8*>(
                    &Blds[buf * 16384 + (rc >> 7) * 8192 + (rc & 127) * 64 + ((g ^ (rc & 7)) << 3)]);
            }
    };

    SA(0, 0, 0); SA(0, 1, 0);
    SB(0, 0, 0); SB(0, 1, 0);
    SB(1, 0, 1); SB(1, 1, 1);
    asm volatile("s_waitcnt vmcnt(4)" ::: "memory");
    __builtin_amdgcn_s_barrier();

#pragma unroll 1
    for (int t = 0; t < NT; ++t) {
        const int abuf = t & 1;
        const int bbuf = t % 3;
        const int b3 = (t + 2) % 3;
        DSRA(abuf, 0);
        DSRB(bbuf, 0, bfr0);
        if (t + 1 < NT) { SA(t + 1, 0, abuf ^ 1); SA(t + 1, 1, abuf ^ 1); }
        __builtin_amdgcn_s_barrier();
        __builtin_amdgcn_s_setprio(1);
#pragma unroll
        for (int ki = 0; ki < 2; ++ki)
#pragma unroll
            for (int mi = 0; mi < 4; ++mi)
#pragma unroll
                for (int nj = 0; nj < 2; ++nj)
                    acc[mi][nj] = __builtin_amdgcn_mfma_f32_16x16x32_bf16(afr[mi][ki], bfr0[nj][ki], acc[mi][nj], 0, 0, 0);
        __builtin_amdgcn_s_setprio(0);
        __builtin_amdgcn_s_barrier();
        DSRB(bbuf, 1, bfr1);
        if (t + 2 < NT) SB(t + 2, 0, b3);
        __builtin_amdgcn_s_barrier();
        __builtin_amdgcn_s_setprio(1);
#pragma unroll
        for (int ki = 0; ki < 2; ++ki)
#pragma unroll
            for (int mi = 0; mi < 4; ++mi)
#pragma unroll
                for (int nj = 0; nj < 2; ++nj)
                    acc[mi][2 + nj] = __builtin_amdgcn_mfma_f32_16x16x32_bf16(afr[mi][ki], bfr1[nj][ki], acc[mi][2 + nj], 0, 0, 0);
        __builtin_amdgcn_s_setprio(0);
        __builtin_amdgcn_s_barrier();
        DSRA(abuf, 1);
        if (t + 2 < NT) SB(t + 2, 1, b3);
        __builtin_amdgcn_s_barrier();
        __builtin_amdgcn_s_setprio(1);
#pragma unroll
        for (int ki = 0; ki < 2; ++ki)
#pragma unroll
            for (int mi = 0; mi < 4; ++mi)
#pragma unroll
                for (int nj = 0; nj < 2; ++nj)
                    acc[4 + mi][2 + nj] = __builtin_amdgcn_mfma_f32_16x16x32_bf16(afr[mi][ki], bfr1[nj][ki], acc[4 + mi][2 + nj], 0, 0, 0);
        __builtin_amdgcn_s_setprio(0);
        __builtin_amdgcn_s_barrier();
        __builtin_amdgcn_s_setprio(1);
#pragma unroll
        for (int ki = 0; ki < 2; ++ki)
#pragma unroll
            for (int mi = 0; mi < 4; ++mi)
#pragma unroll
                for (int nj = 0; nj < 2; ++nj)
                    acc[4 + mi][nj] = __builtin_amdgcn_mfma_f32_16x16x32_bf16(afr[mi][ki], bfr0[nj][ki], acc[4 + mi][nj], 0, 0, 0);
        __builtin_amdgcn_s_setprio(0);
        if (t + 2 < NT) { asm volatile("s_waitcnt vmcnt(4)" ::: "memory"); }
        else { asm volatile("s_waitcnt vmcnt(0)" ::: "memory"); }
        __builtin_amdgcn_s_barrier();
    }

#pragma unroll
    for (int mI = 0; mI < 8; ++mI) {
#pragma unroll
        for (int r = 0; r < 4; ++r) {
            int grow = bm * 256 + wr * 128 + mI * 16 + lk * 4 + r;
            if (grow < Mpad) {
#pragma unroll
                for (int nh = 0; nh < 2; ++nh) {
                    float gg = acc[mI][nh * 2 + 0][r];
                    float uu = acc[mI][nh * 2 + 1][r];
                    float h = gg / (1.f + __expf(-gg)) * uu;
                    int n = bn * 256 + wc * 64 + nh * 32 + l15;
                    int jcol = ((n >> 5) << 4) + (n & 15);
                    __bf16 hb = (__bf16)h;
                    ho[toff(hbase + grow, jcol, HKdim)] = __builtin_bit_cast(u16, hb);
                }
            }
        }
    }
}

// GEMM2 fused: expert (z<32) -> Ye rows; shared (z>=32) K-split -> Yss slices.
__global__ __launch_bounds__(512, 2) void gemm2_fused_kernel(
    const u16* __restrict__ H, const u16* __restrict__ wdT, u16* __restrict__ Ye,
    const u16* __restrict__ Hs, const u16* __restrict__ swdT, u16* __restrict__ Yss,
    const int* __restrict__ counts, const int* __restrict__ poff) {
    __shared__ u16 Alds[2 * 16384];
    __shared__ u16 Blds[3 * 16384];
    constexpr int NT = 16;

    int bm, bn, M, rowbase, AKK, kt0;
    const u16 *aBase, *bBase;
    u16* yo;
    if (blockIdx.z < 32) {
        int lin = blockIdx.x + 16 * (blockIdx.y + 8 * blockIdx.z);
        int e = 31 - (((lin >> 10) << 3) | (lin & 7));
        int j = (lin >> 3) & 127;
        bm = j & 15; bn = j >> 4;
        M = counts[e];
        if (bm * 256 >= M) return;
        rowbase = poff[e];
        aBase = H + (size_t)poff[e] * INTERN;
        bBase = wdT + (size_t)e * 2048 * INTERN;
        yo = Ye; AKK = INTERN; kt0 = 0;
    } else {
        int lin = blockIdx.x + 16 * (blockIdx.y + 8 * (blockIdx.z - 32));
        int swz = (lin & 7) * 32 + (lin >> 3);
        bm = swz & 15; bn = (swz >> 4) & 7;
        int ks = swz >> 7;
        M = T_TOK; rowbase = ks * T_TOK;
        aBase = Hs; bBase = swdT; yo = Yss; AKK = SINTER; kt0 = ks * 16;
    }
    const u16* aCh[2] = { aBase + (size_t)(2 * bm + 0) * (size_t)(128 * AKK) + (size_t)kt0 * 8192,
                          aBase + (size_t)(2 * bm + 1) * (size_t)(128 * AKK) + (size_t)kt0 * 8192 };
    const u16* bCh[2] = { bBase + (size_t)(2 * bn + 0) * (size_t)(128 * AKK) + (size_t)kt0 * 8192,
                          bBase + (size_t)(2 * bn + 1) * (size_t)(128 * AKK) + (size_t)kt0 * 8192 };
    const int tid = threadIdx.x;
    const int t8 = tid * 8;
    const int lane = tid & 63, wv = tid >> 6;
    const int wr = wv >> 2, wc = wv & 3;
    const int l15 = lane & 15, lk = lane >> 4;

    f32x4 acc[8][4];
#pragma unroll
    for (int m = 0; m < 8; ++m)
#pragma unroll
        for (int n = 0; n < 4; ++n) acc[m][n] = {0.f, 0.f, 0.f, 0.f};

    auto SA = [&](int kt, int h, int buf) {
        glds16(aCh[h] + (size_t)kt * 8192 + t8, &Alds[buf * 16384 + h * 8192 + t8]);
        glds16(aCh[h] + (size_t)kt * 8192 + 4096 + t8, &Alds[buf * 16384 + h * 8192 + 4096 + t8]);
    };
    auto SB = [&](int kt, int h, int buf) {
        glds16(bCh[h] + (size_t)kt * 8192 + t8, &Blds[buf * 16384 + h * 8192 + t8]);
        glds16(bCh[h] + (size_t)kt * 8192 + 4096 + t8, &Blds[buf * 16384 + h * 8192 + 4096 + t8]);
    };
    bf16x8 afr[4][2], bfr0[2][2], bfr1[2][2];
    auto DSRA = [&](int buf, int mh) {
#pragma unroll
        for (int mi = 0; mi < 4; ++mi)
#pragma unroll
            for (int ki = 0; ki < 2; ++ki) {
                int rl = wr * 128 + mh * 64 + mi * 16 + l15;
                int g = ki * 4 + lk;
                afr[mi][ki] = *reinterpret_cast<const bf16x8*>(
                    &Alds[buf * 16384 + (rl >> 7) * 8192 + (rl & 127) * 64 + ((g ^ (rl & 7)) << 3)]);
            }
    };
    auto DSRB = [&](int buf, int nh, bf16x8 (&bf)[2][2]) {
#pragma unroll
        for (int nj = 0; nj < 2; ++nj)
#pragma unroll
            for (int ki = 0; ki < 2; ++ki) {
                int rc = wc * 64 + (nh * 2 + nj) * 16 + l15;
                int g = ki * 4 + lk;
                bf[nj][ki] = *reinterpret_cast<const bf16x8*>(
                    &Blds[buf * 16384 + (rc >> 7) * 8192 + (rc & 127) * 64 + ((g ^ (rc & 7)) << 3)]);
            }
    };

    SA(0, 0, 0); SA(0, 1, 0);
    SB(0, 0, 0); SB(0, 1, 0);
    SB(1, 0, 1); SB(1, 1, 1);
    asm volatile("s_waitcnt vmcnt(4)" ::: "memory");
    __builtin_amdgcn_s_barrier();

#pragma unroll 1
    for (int t = 0; t < NT; ++t) {
        const int abuf = t & 1;
        const int bbuf = t % 3;
        const int b3 = (t + 2) % 3;
        DSRA(abuf, 0);
        DSRB(bbuf, 0, bfr0);
        if (t + 1 < NT) { SA(t + 1, 0, abuf ^ 1); SA(t + 1, 1, abuf ^ 1); }
        __builtin_amdgcn_s_barrier();
        __builtin_amdgcn_s_setprio(1);
#pragma unroll
        for (int ki = 0; ki < 2; ++ki)
#pragma unroll
            for (int mi = 0; mi < 4; ++mi)
#pragma unroll
                for (int nj = 0; nj < 2; ++nj)
                    acc[mi][nj] = __builtin_amdgcn_mfma_f32_16x16x32_bf16(afr[mi][ki], bfr0[nj][ki], acc[mi][nj], 0, 0, 0);
        __builtin_amdgcn_s_setprio(0);
        __builtin_amdgcn_s_barrier();
        DSRB(bbuf, 1, bfr1);
        if (t + 2 < NT) SB(t + 2, 0, b3);
        __builtin_amdgcn_s_barrier();
        __builtin_amdgcn_s_setprio(1);
#pragma unroll
        for (int ki = 0; ki < 2; ++ki)
#pragma unroll
            for (int mi = 0; mi < 4; ++mi)
#pragma unroll
                for (int nj = 0; nj < 2; ++nj)
                    acc[mi][2 + nj] = __builtin_amdgcn_mfma_f32_16x16x32_bf16(afr[mi][ki], bfr1[nj][ki], acc[mi][2 + nj], 0, 0, 0);
        __builtin_amdgcn_s_setprio(0);
        __builtin_amdgcn_s_barrier();
        DSRA(abuf, 1);
        if (t + 2 < NT) SB(t + 2, 1, b3);
        __builtin_amdgcn_s_barrier();
        __builtin_amdgcn_s_setprio(1);
#pragma unroll
        for (int ki = 0; ki < 2; ++ki)
#pragma unroll
            for (int mi = 0; mi < 4; ++mi)
#pragma unroll
                for (int nj = 0; nj < 2; ++nj)
                    acc[4 + mi][2 + nj] = __builtin_amdgcn_mfma_f32_16x16x32_bf16(afr[mi][ki], bfr1[nj][ki], acc[4 + mi][2 + nj], 0, 0, 0);
        __builtin_amdgcn_s_setprio(0);
        __builtin_amdgcn_s_barrier();
        __builtin_amdgcn_s_setprio(1);
#pragma unroll
        for (int ki = 0; ki < 2; ++ki)
#pragma unroll
            for (int mi = 0; mi < 4; ++mi)
#pragma unroll
                for (int nj = 0; nj < 2; ++nj)
                    acc[4 + mi][nj] = __builtin_amdgcn_mfma_f32_16x16x32_bf16(afr[mi][ki], bfr0[nj][ki], acc[4 + mi][nj], 0, 0, 0);
        __builtin_amdgcn_s_setprio(0);
        if (t + 2 < NT) { asm volatile("s_waitcnt vmcnt(4)" ::: "memory"); }
        else { asm volatile("s_waitcnt vmcnt(0)" ::: "memory"); }
        __builtin_amdgcn_s_barrier();
    }

#pragma unroll
    for (int mI = 0; mI < 8; ++mI) {
#pragma unroll
        for (int r = 0; r < 4; ++r) {
            int grow = bm * 256 + wr * 128 + mI * 16 + lk * 4 + r;
            if (grow < M) {
                u16* yr = yo + (size_t)(rowbase + grow) * 2048;
#pragma unroll
                for (int ni = 0; ni < 4; ++ni) {
                    int col = bn * 256 + wc * 64 + ni * 16 + l15;
                    __bf16 yb = (__bf16)acc[mI][ni][r];
                    yr[col] = __builtin_bit_cast(u16, yb);
                }
            }
        }
    }
}

// ---------------- combine: out[t] = Yss0[t] + Yss1[t] + sum_r w_r * Ye[row_r] ----------------
__global__ __launch_bounds__(256) void combine_kernel(const u16* __restrict__ Yss, const u16* __restrict__ Ye,
                                                      const int* __restrict__ tok2row, const float* __restrict__ wtok,
                                                      const int* __restrict__ poff, float* __restrict__ out) {
    const int t = blockIdx.x;
    const int c = threadIdx.x * 8;
    bf16x8 v0 = *reinterpret_cast<const bf16x8*>(Yss + (size_t)t * 2048 + c);
    bf16x8 v1 = *reinterpret_cast<const bf16x8*>(Yss + (size_t)(T_TOK + t) * 2048 + c);
    float acc[8];
#pragma unroll
    for (int j = 0; j < 8; ++j) acc[j] = (float)v0[j] + (float)v1[j];
#pragma unroll
    for (int r = 0; r < NTOPK; ++r) {
        int pk = tok2row[t * NTOPK + r];
        int e = pk >> 12, sl = pk & 4095;
        int row = poff[e] + sl;
        float w = wtok[t * NTOPK + r];
        bf16x8 v = *reinterpret_cast<const bf16x8*>(Ye + (size_t)row * 2048 + c);
#pragma unroll
        for (int j = 0; j < 8; ++j) acc[j] += w * (float)v[j];
    }
    float4 o0 = {acc[0], acc[1], acc[2], acc[3]};
    float4 o1 = {acc[4], acc[5], acc[6], acc[7]};
    float4* po = reinterpret_cast<float4*>(out + (size_t)t * 2048 + c);
    po[0] = o0; po[1] = o1;
}

extern "C" void kernel_launch(void* const* d_in, const int* in_sizes, int n_in,
                              void* d_out, int out_size, void* d_ws, size_t ws_size,
                              hipStream_t stream) {
    const float* x = (const float*)d_in[0];
    const float* gate_w = (const float*)d_in[1];
    const float* wg = (const float*)d_in[2];
    const float* wu = (const float*)d_in[3];
    const float* wd = (const float*)d_in[4];
    const float* swg = (const float*)d_in[5];
    const float* swu = (const float*)d_in[6];
    const float* swd = (const float*)d_in[7];
    float* out = (float*)d_out;

    char* ws = (char*)d_ws;
    size_t off = 0;
    auto alloc = [&](size_t bytes) {
        void* p = ws + off;
        off = (off + bytes + 255) & ~(size_t)255;
        return p;
    };
    u16* xbT = (u16*)alloc((size_t)T_TOK * DIMK * 2);                  // 16.8 MB
    u16* H = (u16*)alloc((size_t)MAXPADROWS * INTERN * 2);             // 59.8 MB
    u16* Hs = (u16*)alloc((size_t)T_TOK * SINTER * 2);                 // 16.8 MB
    u16* Ye = (u16*)alloc((size_t)MAXPADROWS * 2048 * 2);              // 119.6 MB
    u16* Yss = (u16*)alloc((size_t)2 * T_TOK * 2048 * 2);              // 33.6 MB
    int* ids = (int*)alloc((size_t)NEXP * T_TOK * 4);
    int* tok2row = (int*)alloc((size_t)T_TOK * NTOPK * 4);
    float* wtok = (float*)alloc((size_t)T_TOK * NTOPK * 4);
    int* counts = (int*)alloc(NEXP * 4);
    int* poff = (int*)alloc(NEXP * 4);
    u16* WcatS = (u16*)alloc((size_t)(2 * SINTER) * DIMK * 2);         // 16.8 MB
    u16* swdT = (u16*)alloc((size_t)DIMK * SINTER * 2);                // 8.4 MB
    u16* WcatE = (u16*)alloc((size_t)NEXP * (2 * INTERN) * DIMK * 2);  // 268.4 MB
    u16* wdT = WcatE;  // alias: wd transpose runs after GEMM1 consumed WcatE (stream-ordered)

    hipMemsetAsync(counts, 0, NEXP * 4, stream);
    cast_x_tiled_kernel<<<(T_TOK * DIMK) / (256 * 8), 256, 0, stream>>>(x, xbT);
    gate_kernel<<<T_TOK, 64, 0, stream>>>(x, gate_w, counts, ids, tok2row, wtok);
    scan_kernel<<<1, 64, 0, stream>>>(counts, poff);

    // weight reshapes (strip-mined, page-friendly reads)
    cat_trans_strip_kernel<DIMK, SINTER, 8><<<dim3(DIMK / 64, 16, 1), 256, 0, stream>>>(swg, swu, WcatS);
    cat_trans_strip_kernel<DIMK, INTERN, 1><<<dim3(DIMK / 64, 2, NEXP), 256, 0, stream>>>(wg, wu, WcatE);
    trans_strip_kernel<SINTER, DIMK, 8><<<dim3(SINTER / 64, 8, 1), 256, 0, stream>>>(swd, swdT);

    // fused GEMM1 (r13 asymmetric-depth 8-phase)
    gemm1_fused_kernel<<<dim3(16, 8, 34), 512, 0, stream>>>(
        xbT, WcatE, H, WcatS, Hs, counts, poff, ids);

    // wd transpose into aliased WcatE region (GEMM1 done by stream order)
    trans_strip_kernel<INTERN, DIMK, 2><<<dim3(INTERN / 64, 2, NEXP), 256, 0, stream>>>(wd, wdT);

    // fused GEMM2 (r13 asymmetric-depth 8-phase)
    gemm2_fused_kernel<<<dim3(16, 8, 34), 512, 0, stream>>>(
        H, wdT, Ye, Hs, swdT, Yss, counts, poff);

    // final combine -> out
    combine_kernel<<<T_TOK, 256, 0, stream>>>(Yss, Ye, tok2row, wtok, poff, out);
}

// Round 16
// 1006.688 us; speedup vs baseline: 1.1017x; 1.0068x over previous
//
#include <hip/hip_runtime.h>
#include <hip/hip_bf16.h>

typedef float f32x4 __attribute__((ext_vector_type(4)));
typedef __bf16 bf16x8 __attribute__((ext_vector_type(8)));
typedef unsigned short u16;

#define T_TOK 4096
#define DIMK 2048
#define INTERN 1024
#define NEXP 32
#define NTOPK 6
#define NGRP 8
#define NTOPG 4
#define SINTER 2048
#define MAXPADROWS 29184

__device__ __forceinline__ void glds16(const void* g, void* l) {
    auto* gp = (const __attribute__((address_space(1))) int*)(g);
    auto* lp = (__attribute__((address_space(3))) int*)(l);
    __builtin_amdgcn_global_load_lds(gp, lp, 16, 0, 0);
}

// Chunked+swizzled layout for [Rows][K] bf16: row-chunks 128, k-chunks 64.
// In-chunk (8192 elems): off = row*64 + ((g ^ (row&7))<<3) + (k&7), g=(k>>3)&7.
__device__ __forceinline__ size_t toff(int row, int k, int K) {
    int g = (k >> 3) & 7;
    return (size_t)(row >> 7) * (size_t)(128 * K) + (size_t)(k >> 6) * 8192 +
           (size_t)((row & 127) * 64 + ((g ^ (row & 7)) << 3) + (k & 7));
}

// ---------------- cast x fp32 -> bf16 chunked ----------------
__global__ __launch_bounds__(256) void cast_x_tiled_kernel(const float* __restrict__ in, u16* __restrict__ out) {
    int gi = (blockIdx.x * 256 + threadIdx.x) * 8;
    int row = gi >> 11, k = gi & 2047;
    const float4* p = reinterpret_cast<const float4*>(in + gi);
    float4 a = p[0], b = p[1];
    bf16x8 v;
    v[0] = (__bf16)a.x; v[1] = (__bf16)a.y; v[2] = (__bf16)a.z; v[3] = (__bf16)a.w;
    v[4] = (__bf16)b.x; v[5] = (__bf16)b.y; v[6] = (__bf16)b.z; v[7] = (__bf16)b.w;
    *reinterpret_cast<bf16x8*>(out + toff(row, k, DIMK)) = v;
}

// ---------------- 512-thread 64x64 tile transpose+convert ----------------
// src [.][JD] fp32, tile (k0,j0); out chunked [rows][KOUT] bf16. CAT: n = ((j>>4)<<5)+s*16+(j&15).
template <bool CAT>
__device__ __forceinline__ void tile_trans_512(const float* __restrict__ src, int JD, int k0, int j0,
                                               u16* __restrict__ ob, int KOUT, int s, float* tile) {
    const int tid = threadIdx.x;
    {
        const int r = tid >> 3, c8 = (tid & 7) * 8;
        float4 v0 = *reinterpret_cast<const float4*>(&src[(size_t)(k0 + r) * JD + j0 + c8]);
        float4 v1 = *reinterpret_cast<const float4*>(&src[(size_t)(k0 + r) * JD + j0 + c8 + 4]);
        float* tp = &tile[r * 65 + c8];
        tp[0] = v0.x; tp[1] = v0.y; tp[2] = v0.z; tp[3] = v0.w;
        tp[4] = v1.x; tp[5] = v1.y; tp[6] = v1.z; tp[7] = v1.w;
    }
    __syncthreads();
    {
        const int jl = tid >> 3, kh = (tid & 7) * 8;
        const int j = j0 + jl;
        const int n = CAT ? (((j >> 4) << 5) + s * 16 + (j & 15)) : j;
        bf16x8 o;
#pragma unroll
        for (int jj = 0; jj < 8; ++jj) o[jj] = (__bf16)tile[(kh + jj) * 65 + jl];
        *reinterpret_cast<bf16x8*>(ob + toff(n, k0 + kh, KOUT)) = o;
    }
}

// ---------------- gate ----------------
__global__ __launch_bounds__(64) void gate_kernel(const float* __restrict__ x, const float* __restrict__ gw,
                                                  int* __restrict__ counts, int* __restrict__ ids,
                                                  int* __restrict__ tok2row, float* __restrict__ wtok) {
    const int t = blockIdx.x;
    const int lane = threadIdx.x;
    __shared__ float logits[NEXP];
    const float4* xr = reinterpret_cast<const float4*>(x + (size_t)t * DIMK);
    for (int e = 0; e < NEXP; ++e) {
        const float4* gr = reinterpret_cast<const float4*>(gw + (size_t)e * DIMK);
        float acc = 0.f;
#pragma unroll
        for (int i = 0; i < DIMK / 4 / 64; ++i) {
            float4 xv = xr[lane + i * 64];
            float4 gv = gr[lane + i * 64];
            acc += xv.x * gv.x + xv.y * gv.y + xv.z * gv.z + xv.w * gv.w;
        }
#pragma unroll
        for (int s = 32; s; s >>= 1) acc += __shfl_xor(acc, s);
        if (lane == 0) logits[e] = acc;
    }
    if (lane != 0) return;
    float sc[NEXP];
#pragma unroll
    for (int e = 0; e < NEXP; ++e) sc[e] = logits[e];
    float mx = sc[0];
#pragma unroll
    for (int e = 1; e < NEXP; ++e) mx = fmaxf(mx, sc[e]);
    float ssum = 0.f;
#pragma unroll
    for (int e = 0; e < NEXP; ++e) { sc[e] = __expf(sc[e] - mx); ssum += sc[e]; }
    const float inv = 1.f / ssum;
    float gsc[NGRP];
#pragma unroll
    for (int g = 0; g < NGRP; ++g) {
        float m2 = sc[g * 4];
#pragma unroll
        for (int j = 1; j < 4; ++j) m2 = fmaxf(m2, sc[g * 4 + j]);
        gsc[g] = m2;
    }
    int gsel = 0;
    for (int r = 0; r < NTOPG; ++r) {
        float bv = -1.f; int bi = 0;
#pragma unroll
        for (int g = 0; g < NGRP; ++g) {
            bool c = (((gsel >> g) & 1) == 0) && (gsc[g] > bv);
            bv = c ? gsc[g] : bv; bi = c ? g : bi;
        }
        gsel |= (1 << bi);
    }
    float msk[NEXP];
#pragma unroll
    for (int e = 0; e < NEXP; ++e) msk[e] = ((gsel >> (e >> 2)) & 1) ? sc[e] : -1.f;
    for (int r = 0; r < NTOPK; ++r) {
        float bv = -3.f; int bi = 0;
#pragma unroll
        for (int e = 0; e < NEXP; ++e) {
            bool c = msk[e] > bv;
            bv = c ? msk[e] : bv; bi = c ? e : bi;
        }
#pragma unroll
        for (int e = 0; e < NEXP; ++e) if (e == bi) msk[e] = -2.f;
        float w = bv * inv;
        int slot = atomicAdd(&counts[bi], 1);
        ids[bi * T_TOK + slot] = t;
        tok2row[t * NTOPK + r] = (bi << 12) | slot;
        wtok[t * NTOPK + r] = w;
    }
}

__global__ void scan_kernel(const int* __restrict__ counts, int* __restrict__ poff) {
    if (threadIdx.x == 0) {
        int o = 0;
        for (int e = 0; e < NEXP; ++e) { poff[e] = o; o += (counts[e] + 127) & ~127; }
    }
}

// ================= r13 GEMM cores as device functions (smem overlay: A=2x16384, B=3x16384 u16) =================
__device__ __forceinline__ void dev_gemm1(u16* smem, const u16* __restrict__ xbT, const u16* __restrict__ b0,
                                          u16* __restrict__ ho, int bm, int bn, int M, int Mpad, int hbase,
                                          int HKdim, bool gath, int e, const int* __restrict__ ids) {
    u16* Alds = smem;
    u16* Blds = smem + 32768;
    constexpr int NT = DIMK / 64;
    const int tid = threadIdx.x;
    const int t8 = tid * 8;
    size_t aSrc[2][2];
#pragma unroll
    for (int h = 0; h < 2; ++h)
#pragma unroll
        for (int j = 0; j < 2; ++j) {
            int drow = j * 64 + (tid >> 3);
            int row = bm * 256 + h * 128 + drow;
            int tok;
            if (gath) { int cr = row < M ? row : M - 1; tok = ids[e * T_TOK + cr]; }
            else tok = row;
            int slot = (tid & 7) ^ (drow & 7) ^ (tok & 7);
            aSrc[h][j] = (size_t)(tok >> 7) * (size_t)(128 * 2048) + (size_t)((tok & 127) * 64 + slot * 8);
        }
    const u16* bCh[2] = { b0 + (size_t)(2 * bn + 0) * (128 * 2048), b0 + (size_t)(2 * bn + 1) * (128 * 2048) };

    const int lane = tid & 63, wv = tid >> 6;
    const int wr = wv >> 2, wc = wv & 3;
    const int l15 = lane & 15, lk = lane >> 4;

    f32x4 acc[8][4];
#pragma unroll
    for (int m = 0; m < 8; ++m)
#pragma unroll
        for (int n = 0; n < 4; ++n) acc[m][n] = {0.f, 0.f, 0.f, 0.f};

    auto SA = [&](int kt, int h, int buf) {
        glds16(xbT + aSrc[h][0] + (size_t)kt * 8192, &Alds[buf * 16384 + h * 8192 + t8]);
        glds16(xbT + aSrc[h][1] + (size_t)kt * 8192, &Alds[buf * 16384 + h * 8192 + 4096 + t8]);
    };
    auto SB = [&](int kt, int h, int buf) {
        glds16(bCh[h] + (size_t)kt * 8192 + t8, &Blds[buf * 16384 + h * 8192 + t8]);
        glds16(bCh[h] + (size_t)kt * 8192 + 4096 + t8, &Blds[buf * 16384 + h * 8192 + 4096 + t8]);
    };
    bf16x8 afr[4][2], bfr0[2][2], bfr1[2][2];
    auto DSRA = [&](int buf, int mh) {
#pragma unroll
        for (int mi = 0; mi < 4; ++mi)
#pragma unroll
            for (int ki = 0; ki < 2; ++ki) {
                int rl = wr * 128 + mh * 64 + mi * 16 + l15;
                int g = ki * 4 + lk;
                afr[mi][ki] = *reinterpret_cast<const bf16x8*>(
                    &Alds[buf * 16384 + (rl >> 7) * 8192 + (rl & 127) * 64 + ((g ^ (rl & 7)) << 3)]);
            }
    };
    auto DSRB = [&](int buf, int nh, bf16x8 (&bf)[2][2]) {
#pragma unroll
        for (int nj = 0; nj < 2; ++nj)
#pragma unroll
            for (int ki = 0; ki < 2; ++ki) {
                int rc = wc * 64 + (nh * 2 + nj) * 16 + l15;
                int g = ki * 4 + lk;
                bf[nj][ki] = *reinterpret_cast<const bf16x8*>(
                    &Blds[buf * 16384 + (rc >> 7) * 8192 + (rc & 127) * 64 + ((g ^ (rc & 7)) << 3)]);
            }
    };

    SA(0, 0, 0); SA(0, 1, 0);
    SB(0, 0, 0); SB(0, 1, 0);
    SB(1, 0, 1); SB(1, 1, 1);
    asm volatile("s_waitcnt vmcnt(4)" ::: "memory");
    __builtin_amdgcn_s_barrier();

#pragma unroll 1
    for (int t = 0; t < NT; ++t) {
        const int abuf = t & 1;
        const int bbuf = t % 3;
        const int b3 = (t + 2) % 3;
        DSRA(abuf, 0);
        DSRB(bbuf, 0, bfr0);
        if (t + 1 < NT) { SA(t + 1, 0, abuf ^ 1); SA(t + 1, 1, abuf ^ 1); }
        __builtin_amdgcn_s_barrier();
        __builtin_amdgcn_s_setprio(1);
#pragma unroll
        for (int ki = 0; ki < 2; ++ki)
#pragma unroll
            for (int mi = 0; mi < 4; ++mi)
#pragma unroll
                for (int nj = 0; nj < 2; ++nj)
                    acc[mi][nj] = __builtin_amdgcn_mfma_f32_16x16x32_bf16(afr[mi][ki], bfr0[nj][ki], acc[mi][nj], 0, 0, 0);
        __builtin_amdgcn_s_setprio(0);
        __builtin_amdgcn_s_barrier();
        DSRB(bbuf, 1, bfr1);
        if (t + 2 < NT) SB(t + 2, 0, b3);
        __builtin_amdgcn_s_barrier();
        __builtin_amdgcn_s_setprio(1);
#pragma unroll
        for (int ki = 0; ki < 2; ++ki)
#pragma unroll
            for (int mi = 0; mi < 4; ++mi)
#pragma unroll
                for (int nj = 0; nj < 2; ++nj)
                    acc[mi][2 + nj] = __builtin_amdgcn_mfma_f32_16x16x32_bf16(afr[mi][ki], bfr1[nj][ki], acc[mi][2 + nj], 0, 0, 0);
        __builtin_amdgcn_s_setprio(0);
        __builtin_amdgcn_s_barrier();
        DSRA(abuf, 1);
        if (t + 2 < NT) SB(t + 2, 1, b3);
        __builtin_amdgcn_s_barrier();
        __builtin_amdgcn_s_setprio(1);
#pragma unroll
        for (int ki = 0; ki < 2; ++ki)
#pragma unroll
            for (int mi = 0; mi < 4; ++mi)
#pragma unroll
                for (int nj = 0; nj < 2; ++nj)
                    acc[4 + mi][2 + nj] = __builtin_amdgcn_mfma_f32_16x16x32_bf16(afr[mi][ki], bfr1[nj][ki], acc[4 + mi][2 + nj], 0, 0, 0);
        __builtin_amdgcn_s_setprio(0);
        __builtin_amdgcn_s_barrier();
        __builtin_amdgcn_s_setprio(1);
#pragma unroll
        for (int ki = 0; ki < 2; ++ki)
#pragma unroll
            for (int mi = 0; mi < 4; ++mi)
#pragma unroll
                for (int nj = 0; nj < 2; ++nj)
                    acc[4 + mi][nj] = __builtin_amdgcn_mfma_f32_16x16x32_bf16(afr[mi][ki], bfr0[nj][ki], acc[4 + mi][nj], 0, 0, 0);
        __builtin_amdgcn_s_setprio(0);
        if (t + 2 < NT) { asm volatile("s_waitcnt vmcnt(4)" ::: "memory"); }
        else { asm volatile("s_waitcnt vmcnt(0)" ::: "memory"); }
        __builtin_amdgcn_s_barrier();
    }

#pragma unroll
    for (int mI = 0; mI < 8; ++mI) {
#pragma unroll
        for (int r = 0; r < 4; ++r) {
            int grow = bm * 256 + wr * 128 + mI * 16 + lk * 4 + r;
            if (grow < Mpad) {
#pragma unroll
                for (int nh = 0; nh < 2; ++nh) {
                    float gg = acc[mI][nh * 2 + 0][r];
                    float uu = acc[mI][nh * 2 + 1][r];
                    float h = gg / (1.f + __expf(-gg)) * uu;
                    int n = bn * 256 + wc * 64 + nh * 32 + l15;
                    int jcol = ((n >> 5) << 4) + (n & 15);
                    __bf16 hb = (__bf16)h;
                    ho[toff(hbase + grow, jcol, HKdim)] = __builtin_bit_cast(u16, hb);
                }
            }
        }
    }
}

__device__ __forceinline__ void dev_gemm2(u16* smem, const u16* __restrict__ aBase, const u16* __restrict__ bBase,
                                          u16* __restrict__ yo, int bm, int bn, int M, int rowbase, int AKK, int kt0) {
    u16* Alds = smem;
    u16* Blds = smem + 32768;
    constexpr int NT = 16;
    const u16* aCh[2] = { aBase + (size_t)(2 * bm + 0) * (size_t)(128 * AKK) + (size_t)kt0 * 8192,
                          aBase + (size_t)(2 * bm + 1) * (size_t)(128 * AKK) + (size_t)kt0 * 8192 };
    const u16* bCh[2] = { bBase + (size_t)(2 * bn + 0) * (size_t)(128 * AKK) + (size_t)kt0 * 8192,
                          bBase + (size_t)(2 * bn + 1) * (size_t)(128 * AKK) + (size_t)kt0 * 8192 };
    const int tid = threadIdx.x;
    const int t8 = tid * 8;
    const int lane = tid & 63, wv = tid >> 6;
    const int wr = wv >> 2, wc = wv & 3;
    const int l15 = lane & 15, lk = lane >> 4;

    f32x4 acc[8][4];
#pragma unroll
    for (int m = 0; m < 8; ++m)
#pragma unroll
        for (int n = 0; n < 4; ++n) acc[m][n] = {0.f, 0.f, 0.f, 0.f};

    auto SA = [&](int kt, int h, int buf) {
        glds16(aCh[h] + (size_t)kt * 8192 + t8, &Alds[buf * 16384 + h * 8192 + t8]);
        glds16(aCh[h] + (size_t)kt * 8192 + 4096 + t8, &Alds[buf * 16384 + h * 8192 + 4096 + t8]);
    };
    auto SB = [&](int kt, int h, int buf) {
        glds16(bCh[h] + (size_t)kt * 8192 + t8, &Blds[buf * 16384 + h * 8192 + t8]);
        glds16(bCh[h] + (size_t)kt * 8192 + 4096 + t8, &Blds[buf * 16384 + h * 8192 + 4096 + t8]);
    };
    bf16x8 afr[4][2], bfr0[2][2], bfr1[2][2];
    auto DSRA = [&](int buf, int mh) {
#pragma unroll
        for (int mi = 0; mi < 4; ++mi)
#pragma unroll
            for (int ki = 0; ki < 2; ++ki) {
                int rl = wr * 128 + mh * 64 + mi * 16 + l15;
                int g = ki * 4 + lk;
                afr[mi][ki] = *reinterpret_cast<const bf16x8*>(
                    &Alds[buf * 16384 + (rl >> 7) * 8192 + (rl & 127) * 64 + ((g ^ (rl & 7)) << 3)]);
            }
    };
    auto DSRB = [&](int buf, int nh, bf16x8 (&bf)[2][2]) {
#pragma unroll
        for (int nj = 0; nj < 2; ++nj)
#pragma unroll
            for (int ki = 0; ki < 2; ++ki) {
                int rc = wc * 64 + (nh * 2 + nj) * 16 + l15;
                int g = ki * 4 + lk;
                bf[nj][ki] = *reinterpret_cast<const bf16x8*>(
                    &Blds[buf * 16384 + (rc >> 7) * 8192 + (rc & 127) * 64 + ((g ^ (rc & 7)) << 3)]);
            }
    };

    SA(0, 0, 0); SA(0, 1, 0);
    SB(0, 0, 0); SB(0, 1, 0);
    SB(1, 0, 1); SB(1, 1, 1);
    asm volatile("s_waitcnt vmcnt(4)" ::: "memory");
    __builtin_amdgcn_s_barrier();

#pragma unroll 1
    for (int t = 0; t < NT; ++t) {
        const int abuf = t & 1;
        const int bbuf = t % 3;
        const int b3 = (t + 2) % 3;
        DSRA(abuf, 0);
        DSRB(bbuf, 0, bfr0);
        if (t + 1 < NT) { SA(t + 1, 0, abuf ^ 1); SA(t + 1, 1, abuf ^ 1); }
        __builtin_amdgcn_s_barrier();
        __builtin_amdgcn_s_setprio(1);
#pragma unroll
        for (int ki = 0; ki < 2; ++ki)
#pragma unroll
            for (int mi = 0; mi < 4; ++mi)
#pragma unroll
                for (int nj = 0; nj < 2; ++nj)
                    acc[mi][nj] = __builtin_amdgcn_mfma_f32_16x16x32_bf16(afr[mi][ki], bfr0[nj][ki], acc[mi][nj], 0, 0, 0);
        __builtin_amdgcn_s_setprio(0);
        __builtin_amdgcn_s_barrier();
        DSRB(bbuf, 1, bfr1);
        if (t + 2 < NT) SB(t + 2, 0, b3);
        __builtin_amdgcn_s_barrier();
        __builtin_amdgcn_s_setprio(1);
#pragma unroll
        for (int ki = 0; ki < 2; ++ki)
#pragma unroll
            for (int mi = 0; mi < 4; ++mi)
#pragma unroll
                for (int nj = 0; nj < 2; ++nj)
                    acc[mi][2 + nj] = __builtin_amdgcn_mfma_f32_16x16x32_bf16(afr[mi][ki], bfr1[nj][ki], acc[mi][2 + nj], 0, 0, 0);
        __builtin_amdgcn_s_setprio(0);
        __builtin_amdgcn_s_barrier();
        DSRA(abuf, 1);
        if (t + 2 < NT) SB(t + 2, 1, b3);
        __builtin_amdgcn_s_barrier();
        __builtin_amdgcn_s_setprio(1);
#pragma unroll
        for (int ki = 0; ki < 2; ++ki)
#pragma unroll
            for (int mi = 0; mi < 4; ++mi)
#pragma unroll
                for (int nj = 0; nj < 2; ++nj)
                    acc[4 + mi][2 + nj] = __builtin_amdgcn_mfma_f32_16x16x32_bf16(afr[mi][ki], bfr1[nj][ki], acc[4 + mi][2 + nj], 0, 0, 0);
        __builtin_amdgcn_s_setprio(0);
        __builtin_amdgcn_s_barrier();
        __builtin_amdgcn_s_setprio(1);
#pragma unroll
        for (int ki = 0; ki < 2; ++ki)
#pragma unroll
            for (int mi = 0; mi < 4; ++mi)
#pragma unroll
                for (int nj = 0; nj < 2; ++nj)
                    acc[4 + mi][nj] = __builtin_amdgcn_mfma_f32_16x16x32_bf16(afr[mi][ki], bfr0[nj][ki], acc[4 + mi][nj], 0, 0, 0);
        __builtin_amdgcn_s_setprio(0);
        if (t + 2 < NT) { asm volatile("s_waitcnt vmcnt(4)" ::: "memory"); }
        else { asm volatile("s_waitcnt vmcnt(0)" ::: "memory"); }
        __builtin_amdgcn_s_barrier();
    }

#pragma unroll
    for (int mI = 0; mI < 8; ++mI) {
#pragma unroll
        for (int r = 0; r < 4; ++r) {
            int grow = bm * 256 + wr * 128 + mI * 16 + lk * 4 + r;
            if (grow < M) {
                u16* yr = yo + (size_t)(rowbase + grow) * 2048;
#pragma unroll
                for (int ni = 0; ni < 4; ++ni) {
                    int col = bn * 256 + wc * 64 + ni * 16 + l15;
                    __bf16 yb = (__bf16)acc[mI][ni][r];
                    yr[col] = __builtin_bit_cast(u16, yb);
                }
            }
        }
    }
}

// ---------------- P0: small reshapes (WcatS cat + swdT) ----------------
__global__ __launch_bounds__(512, 2) void p0_trans_kernel(const float* __restrict__ swg, const float* __restrict__ swu,
                                                          const float* __restrict__ swd,
                                                          u16* __restrict__ WcatS, u16* __restrict__ swdT) {
    __shared__ float tile[64 * 65];
    int lin = blockIdx.x;
    if (lin < 2048) {
        int s = lin >> 10, v = lin & 1023;
        int kt = (v >> 5) & 31, jt = v & 31;
        tile_trans_512<true>((s ? swu : swg), SINTER, kt * 64, jt * 64, WcatS, DIMK, s, tile);
    } else {
        int v = lin - 2048;
        int kt = v >> 5, jt = v & 31;
        tile_trans_512<false>(swd, DIMK, kt * 64, jt * 64, swdT, SINTER, 0, tile);
    }
}

// ---------------- D1: sGEMM1 (1/129) interleaved with WcatE transpose ----------------
__global__ __launch_bounds__(512, 2) void d1_kernel(const u16* __restrict__ xbT, const u16* __restrict__ WcatS,
                                                    u16* __restrict__ Hs,
                                                    const float* __restrict__ wg, const float* __restrict__ wu,
                                                    u16* __restrict__ WcatE) {
    __shared__ u16 smem[81920];
    int lin = blockIdx.x;
    int t = lin / 129, r = lin % 129;
    if (r == 0) {
        int swz = (t & 7) * 32 + (t >> 3);
        int bm = swz & 15, bn = swz >> 4;
        dev_gemm1(smem, xbT, WcatS, Hs, bm, bn, T_TOK, T_TOK, 0, SINTER, false, 0, nullptr);
    } else {
        int u = t * 128 + (r - 1);
        int e = u >> 10, v = u & 1023;
        int s = (v >> 9) & 1, kt = (v >> 4) & 31, jt = v & 15;
        const float* src = (s ? wu : wg) + (size_t)e * DIMK * INTERN;
        u16* ob = WcatE + (size_t)e * 2048 * DIMK;
        tile_trans_512<true>(src, INTERN, kt * 64, jt * 64, ob, DIMK, s, (float*)smem);
    }
}

// ---------------- D2: eGEMM1 + sGEMM2 (1/17) + optional wdT transpose tail ----------------
__global__ __launch_bounds__(512, 2) void d2_kernel(const u16* __restrict__ xbT, const u16* __restrict__ WcatE,
                                                    u16* __restrict__ H,
                                                    const u16* __restrict__ Hs, const u16* __restrict__ swdT,
                                                    u16* __restrict__ Yss,
                                                    const float* __restrict__ wd, u16* __restrict__ wdTout,
                                                    const int* __restrict__ counts, const int* __restrict__ poff,
                                                    const int* __restrict__ ids) {
    __shared__ u16 smem[81920];
    int lin = blockIdx.x;
    if (lin < 4352) {
        int t = lin / 17, r = lin % 17;
        if (r == 16) {
            int swz = (t & 7) * 32 + (t >> 3);
            int bm = swz & 15, bn = (swz >> 4) & 7, ks = swz >> 7;
            dev_gemm2(smem, Hs, swdT, Yss, bm, bn, T_TOK, ks * T_TOK, SINTER, ks * 16);
        } else {
            int u = t * 16 + r;
            int e = 31 - (((u >> 10) << 3) | (u & 7));
            int j = (u >> 3) & 127;
            int bm = j & 15, bn = j >> 4;
            int M = counts[e];
            if (bm * 256 >= M) return;
            dev_gemm1(smem, xbT, WcatE + (size_t)e * 2048 * DIMK, H,
                      bm, bn, M, (M + 127) & ~127, poff[e], INTERN, true, e, ids);
        }
    } else {
        int u = lin - 4352;
        int e = u >> 9, v = u & 511;
        int kt = v >> 5, jt = v & 31;
        tile_trans_512<false>(wd + (size_t)e * INTERN * DIMK, DIMK, kt * 64, jt * 64,
                              wdTout + (size_t)e * DIMK * INTERN, INTERN, 0, (float*)smem);
    }
}

// ---------------- standalone wdT transpose (fallback when ws too small) ----------------
__global__ __launch_bounds__(512, 2) void wdt_kernel(const float* __restrict__ wd, u16* __restrict__ wdTout) {
    __shared__ float tile[64 * 65];
    int u = blockIdx.x;
    int e = u >> 9, v = u & 511;
    tile_trans_512<false>(wd + (size_t)e * INTERN * DIMK, DIMK, (v >> 5) * 64, (v & 31) * 64,
                          wdTout + (size_t)e * DIMK * INTERN, INTERN, 0, tile);
}

// ---------------- D3: eGEMM2 ----------------
__global__ __launch_bounds__(512, 2) void d3_kernel(const u16* __restrict__ H, const u16* __restrict__ wdTu,
                                                    u16* __restrict__ Ye,
                                                    const int* __restrict__ counts, const int* __restrict__ poff) {
    __shared__ u16 smem[81920];
    int u = blockIdx.x;
    int e = 31 - (((u >> 10) << 3) | (u & 7));
    int j = (u >> 3) & 127;
    int bm = j & 15, bn = j >> 4;
    int M = counts[e];
    if (bm * 256 >= M) return;
    dev_gemm2(smem, H + (size_t)poff[e] * INTERN, wdTu + (size_t)e * 2048 * INTERN, Ye,
              bm, bn, M, poff[e], INTERN, 0);
}

// ---------------- combine: out[t] = Yss0[t] + Yss1[t] + sum_r w_r * Ye[row_r] ----------------
__global__ __launch_bounds__(256) void combine_kernel(const u16* __restrict__ Yss, const u16* __restrict__ Ye,
                                                      const int* __restrict__ tok2row, const float* __restrict__ wtok,
                                                      const int* __restrict__ poff, float* __restrict__ out) {
    const int t = blockIdx.x;
    const int c = threadIdx.x * 8;
    bf16x8 v0 = *reinterpret_cast<const bf16x8*>(Yss + (size_t)t * 2048 + c);
    bf16x8 v1 = *reinterpret_cast<const bf16x8*>(Yss + (size_t)(T_TOK + t) * 2048 + c);
    float acc[8];
#pragma unroll
    for (int j = 0; j < 8; ++j) acc[j] = (float)v0[j] + (float)v1[j];
#pragma unroll
    for (int r = 0; r < NTOPK; ++r) {
        int pk = tok2row[t * NTOPK + r];
        int e = pk >> 12, sl = pk & 4095;
        int row = poff[e] + sl;
        float w = wtok[t * NTOPK + r];
        bf16x8 v = *reinterpret_cast<const bf16x8*>(Ye + (size_t)row * 2048 + c);
#pragma unroll
        for (int j = 0; j < 8; ++j) acc[j] += w * (float)v[j];
    }
    float4 o0 = {acc[0], acc[1], acc[2], acc[3]};
    float4 o1 = {acc[4], acc[5], acc[6], acc[7]};
    float4* po = reinterpret_cast<float4*>(out + (size_t)t * 2048 + c);
    po[0] = o0; po[1] = o1;
}

extern "C" void kernel_launch(void* const* d_in, const int* in_sizes, int n_in,
                              void* d_out, int out_size, void* d_ws, size_t ws_size,
                              hipStream_t stream) {
    const float* x = (const float*)d_in[0];
    const float* gate_w = (const float*)d_in[1];
    const float* wg = (const float*)d_in[2];
    const float* wu = (const float*)d_in[3];
    const float* wd = (const float*)d_in[4];
    const float* swg = (const float*)d_in[5];
    const float* swu = (const float*)d_in[6];
    const float* swd = (const float*)d_in[7];
    float* out = (float*)d_out;

    char* ws = (char*)d_ws;
    size_t off = 0;
    auto alloc = [&](size_t bytes) {
        void* p = ws + off;
        off = (off + bytes + 255) & ~(size_t)255;
        return p;
    };
    u16* xbT = (u16*)alloc((size_t)T_TOK * DIMK * 2);                  // 16.8 MB
    u16* H = (u16*)alloc((size_t)MAXPADROWS * INTERN * 2);             // 59.8 MB
    u16* Hs = (u16*)alloc((size_t)T_TOK * SINTER * 2);                 // 16.8 MB
    u16* Ye = (u16*)alloc((size_t)MAXPADROWS * 2048 * 2);              // 119.6 MB
    u16* Yss = (u16*)alloc((size_t)2 * T_TOK * 2048 * 2);              // 33.6 MB
    int* ids = (int*)alloc((size_t)NEXP * T_TOK * 4);
    int* tok2row = (int*)alloc((size_t)T_TOK * NTOPK * 4);
    float* wtok = (float*)alloc((size_t)T_TOK * NTOPK * 4);
    int* counts = (int*)alloc(NEXP * 4);
    int* poff = (int*)alloc(NEXP * 4);
    u16* WcatS = (u16*)alloc((size_t)(2 * SINTER) * DIMK * 2);         // 16.8 MB
    u16* swdT = (u16*)alloc((size_t)DIMK * SINTER * 2);                // 8.4 MB
    u16* WcatE = (u16*)alloc((size_t)NEXP * (2 * INTERN) * DIMK * 2);  // 268.4 MB
    u16* wdT2 = (u16*)alloc((size_t)NEXP * INTERN * DIMK * 2);         // 134.2 MB (optional)
    const bool wdFused = (off <= ws_size);
    u16* wdTuse = wdFused ? wdT2 : WcatE;  // fallback aliases WcatE (written after D2)

    hipMemsetAsync(counts, 0, NEXP * 4, stream);
    cast_x_tiled_kernel<<<(T_TOK * DIMK) / (256 * 8), 256, 0, stream>>>(x, xbT);
    gate_kernel<<<T_TOK, 64, 0, stream>>>(x, gate_w, counts, ids, tok2row, wtok);
    scan_kernel<<<1, 64, 0, stream>>>(counts, poff);

    // P0: small reshapes
    p0_trans_kernel<<<3072, 512, 0, stream>>>(swg, swu, swd, WcatS, swdT);

    // D1: shared GEMM1 interleaved with WcatE transpose
    d1_kernel<<<33024, 512, 0, stream>>>(xbT, WcatS, Hs, wg, wu, WcatE);

    // D2: expert GEMM1 + shared GEMM2 (+ wd transpose if ws permits)
    d2_kernel<<<wdFused ? (4352 + 16384) : 4352, 512, 0, stream>>>(
        xbT, WcatE, H, Hs, swdT, Yss, wd, wdTuse, counts, poff, ids);

    if (!wdFused)
        wdt_kernel<<<16384, 512, 0, stream>>>(wd, wdTuse);

    // D3: expert GEMM2
    d3_kernel<<<4096, 512, 0, stream>>>(H, wdTuse, Ye, counts, poff);

    // final combine -> out
    combine_kernel<<<T_TOK, 256, 0, stream>>>(Yss, Ye, tok2row, wtok, poff, out);
}

// Round 17
// 948.971 us; speedup vs baseline: 1.1687x; 1.0608x over previous
//
#include <hip/hip_runtime.h>
#include <hip/hip_bf16.h>

typedef float f32x4 __attribute__((ext_vector_type(4)));
typedef __bf16 bf16x8 __attribute__((ext_vector_type(8)));
typedef unsigned short u16;

#define T_TOK 4096
#define DIMK 2048
#define INTERN 1024
#define NEXP 32
#define NTOPK 6
#define NGRP 8
#define NTOPG 4
#define SINTER 2048
#define MAXPADROWS 29184

__device__ __forceinline__ void glds16(const void* g, void* l) {
    auto* gp = (const __attribute__((address_space(1))) int*)(g);
    auto* lp = (__attribute__((address_space(3))) int*)(l);
    __builtin_amdgcn_global_load_lds(gp, lp, 16, 0, 0);
}

// Chunked+swizzled layout for [Rows][K] bf16: row-chunks 128, k-chunks 64.
// In-chunk (8192 elems): off = row*64 + ((g ^ (row&7))<<3) + (k&7), g=(k>>3)&7.
__device__ __forceinline__ size_t toff(int row, int k, int K) {
    int g = (k >> 3) & 7;
    return (size_t)(row >> 7) * (size_t)(128 * K) + (size_t)(k >> 6) * 8192 +
           (size_t)((row & 127) * 64 + ((g ^ (row & 7)) << 3) + (k & 7));
}

// ---------------- cast x fp32 -> bf16 chunked ----------------
__global__ __launch_bounds__(256) void cast_x_tiled_kernel(const float* __restrict__ in, u16* __restrict__ out) {
    int gi = (blockIdx.x * 256 + threadIdx.x) * 8;
    int row = gi >> 11, k = gi & 2047;
    const float4* p = reinterpret_cast<const float4*>(in + gi);
    float4 a = p[0], b = p[1];
    bf16x8 v;
    v[0] = (__bf16)a.x; v[1] = (__bf16)a.y; v[2] = (__bf16)a.z; v[3] = (__bf16)a.w;
    v[4] = (__bf16)b.x; v[5] = (__bf16)b.y; v[6] = (__bf16)b.z; v[7] = (__bf16)b.w;
    *reinterpret_cast<bf16x8*>(out + toff(row, k, DIMK)) = v;
}

// ---------------- 512-thread 64x64 tile transpose+convert ----------------
// src [.][JD] fp32, tile (k0,j0); out chunked [rows][KOUT] bf16. CAT: n = ((j>>4)<<5)+s*16+(j&15).
template <bool CAT>
__device__ __forceinline__ void tile_trans_512(const float* __restrict__ src, int JD, int k0, int j0,
                                               u16* __restrict__ ob, int KOUT, int s, float* tile) {
    const int tid = threadIdx.x;
    {
        const int r = tid >> 3, c8 = (tid & 7) * 8;
        float4 v0 = *reinterpret_cast<const float4*>(&src[(size_t)(k0 + r) * JD + j0 + c8]);
        float4 v1 = *reinterpret_cast<const float4*>(&src[(size_t)(k0 + r) * JD + j0 + c8 + 4]);
        float* tp = &tile[r * 65 + c8];
        tp[0] = v0.x; tp[1] = v0.y; tp[2] = v0.z; tp[3] = v0.w;
        tp[4] = v1.x; tp[5] = v1.y; tp[6] = v1.z; tp[7] = v1.w;
    }
    __syncthreads();
    {
        const int jl = tid >> 3, kh = (tid & 7) * 8;
        const int j = j0 + jl;
        const int n = CAT ? (((j >> 4) << 5) + s * 16 + (j & 15)) : j;
        bf16x8 o;
#pragma unroll
        for (int jj = 0; jj < 8; ++jj) o[jj] = (__bf16)tile[(kh + jj) * 65 + jl];
        *reinterpret_cast<bf16x8*>(ob + toff(n, k0 + kh, KOUT)) = o;
    }
}

// ---------------- all reshapes in one high-occupancy dispatch ----------------
// blocks [0,2048): WcatS cat; [2048,3072): swdT; [3072,35840): WcatE cat.
__global__ __launch_bounds__(512) void trans_all_kernel(
    const float* __restrict__ swg, const float* __restrict__ swu, const float* __restrict__ swd,
    const float* __restrict__ wg, const float* __restrict__ wu,
    u16* __restrict__ WcatS, u16* __restrict__ swdT, u16* __restrict__ WcatE) {
    __shared__ float tile[64 * 65];
    int lin = blockIdx.x;
    if (lin < 2048) {
        int s = lin >> 10, v = lin & 1023;
        int kt = (v >> 5) & 31, jt = v & 31;
        tile_trans_512<true>((s ? swu : swg), SINTER, kt * 64, jt * 64, WcatS, DIMK, s, tile);
    } else if (lin < 3072) {
        int v = lin - 2048;
        int kt = v >> 5, jt = v & 31;
        tile_trans_512<false>(swd, DIMK, kt * 64, jt * 64, swdT, SINTER, 0, tile);
    } else {
        int u = lin - 3072;
        int e = u >> 10, v = u & 1023;
        int s = (v >> 9) & 1, kt = (v >> 4) & 31, jt = v & 15;
        const float* src = (s ? wu : wg) + (size_t)e * DIMK * INTERN;
        u16* ob = WcatE + (size_t)e * 2048 * DIMK;
        tile_trans_512<true>(src, INTERN, kt * 64, jt * 64, ob, DIMK, s, tile);
    }
}

// ---------------- gate ----------------
__global__ __launch_bounds__(64) void gate_kernel(const float* __restrict__ x, const float* __restrict__ gw,
                                                  int* __restrict__ counts, int* __restrict__ ids,
                                                  int* __restrict__ tok2row, float* __restrict__ wtok) {
    const int t = blockIdx.x;
    const int lane = threadIdx.x;
    __shared__ float logits[NEXP];
    const float4* xr = reinterpret_cast<const float4*>(x + (size_t)t * DIMK);
    for (int e = 0; e < NEXP; ++e) {
        const float4* gr = reinterpret_cast<const float4*>(gw + (size_t)e * DIMK);
        float acc = 0.f;
#pragma unroll
        for (int i = 0; i < DIMK / 4 / 64; ++i) {
            float4 xv = xr[lane + i * 64];
            float4 gv = gr[lane + i * 64];
            acc += xv.x * gv.x + xv.y * gv.y + xv.z * gv.z + xv.w * gv.w;
        }
#pragma unroll
        for (int s = 32; s; s >>= 1) acc += __shfl_xor(acc, s);
        if (lane == 0) logits[e] = acc;
    }
    if (lane != 0) return;
    float sc[NEXP];
#pragma unroll
    for (int e = 0; e < NEXP; ++e) sc[e] = logits[e];
    float mx = sc[0];
#pragma unroll
    for (int e = 1; e < NEXP; ++e) mx = fmaxf(mx, sc[e]);
    float ssum = 0.f;
#pragma unroll
    for (int e = 0; e < NEXP; ++e) { sc[e] = __expf(sc[e] - mx); ssum += sc[e]; }
    const float inv = 1.f / ssum;
    float gsc[NGRP];
#pragma unroll
    for (int g = 0; g < NGRP; ++g) {
        float m2 = sc[g * 4];
#pragma unroll
        for (int j = 1; j < 4; ++j) m2 = fmaxf(m2, sc[g * 4 + j]);
        gsc[g] = m2;
    }
    int gsel = 0;
    for (int r = 0; r < NTOPG; ++r) {
        float bv = -1.f; int bi = 0;
#pragma unroll
        for (int g = 0; g < NGRP; ++g) {
            bool c = (((gsel >> g) & 1) == 0) && (gsc[g] > bv);
            bv = c ? gsc[g] : bv; bi = c ? g : bi;
        }
        gsel |= (1 << bi);
    }
    float msk[NEXP];
#pragma unroll
    for (int e = 0; e < NEXP; ++e) msk[e] = ((gsel >> (e >> 2)) & 1) ? sc[e] : -1.f;
    for (int r = 0; r < NTOPK; ++r) {
        float bv = -3.f; int bi = 0;
#pragma unroll
        for (int e = 0; e < NEXP; ++e) {
            bool c = msk[e] > bv;
            bv = c ? msk[e] : bv; bi = c ? e : bi;
        }
#pragma unroll
        for (int e = 0; e < NEXP; ++e) if (e == bi) msk[e] = -2.f;
        float w = bv * inv;
        int slot = atomicAdd(&counts[bi], 1);
        ids[bi * T_TOK + slot] = t;
        tok2row[t * NTOPK + r] = (bi << 12) | slot;
        wtok[t * NTOPK + r] = w;
    }
}

__global__ void scan_kernel(const int* __restrict__ counts, int* __restrict__ poff) {
    if (threadIdx.x == 0) {
        int o = 0;
        for (int e = 0; e < NEXP; ++e) { poff[e] = o; o += (counts[e] + 127) & ~127; }
    }
}

// ================= r13 GEMM cores as device functions (smem overlay: A=2x16384, B=3x16384 u16) =================
__device__ __forceinline__ void dev_gemm1(u16* smem, const u16* __restrict__ xbT, const u16* __restrict__ b0,
                                          u16* __restrict__ ho, int bm, int bn, int M, int Mpad, int hbase,
                                          int HKdim, bool gath, int e, const int* __restrict__ ids) {
    u16* Alds = smem;
    u16* Blds = smem + 32768;
    constexpr int NT = DIMK / 64;
    const int tid = threadIdx.x;
    const int t8 = tid * 8;
    size_t aSrc[2][2];
#pragma unroll
    for (int h = 0; h < 2; ++h)
#pragma unroll
        for (int j = 0; j < 2; ++j) {
            int drow = j * 64 + (tid >> 3);
            int row = bm * 256 + h * 128 + drow;
            int tok;
            if (gath) { int cr = row < M ? row : M - 1; tok = ids[e * T_TOK + cr]; }
            else tok = row;
            int slot = (tid & 7) ^ (drow & 7) ^ (tok & 7);
            aSrc[h][j] = (size_t)(tok >> 7) * (size_t)(128 * 2048) + (size_t)((tok & 127) * 64 + slot * 8);
        }
    const u16* bCh[2] = { b0 + (size_t)(2 * bn + 0) * (128 * 2048), b0 + (size_t)(2 * bn + 1) * (128 * 2048) };

    const int lane = tid & 63, wv = tid >> 6;
    const int wr = wv >> 2, wc = wv & 3;
    const int l15 = lane & 15, lk = lane >> 4;

    f32x4 acc[8][4];
#pragma unroll
    for (int m = 0; m < 8; ++m)
#pragma unroll
        for (int n = 0; n < 4; ++n) acc[m][n] = {0.f, 0.f, 0.f, 0.f};

    auto SA = [&](int kt, int h, int buf) {
        glds16(xbT + aSrc[h][0] + (size_t)kt * 8192, &Alds[buf * 16384 + h * 8192 + t8]);
        glds16(xbT + aSrc[h][1] + (size_t)kt * 8192, &Alds[buf * 16384 + h * 8192 + 4096 + t8]);
    };
    auto SB = [&](int kt, int h, int buf) {
        glds16(bCh[h] + (size_t)kt * 8192 + t8, &Blds[buf * 16384 + h * 8192 + t8]);
        glds16(bCh[h] + (size_t)kt * 8192 + 4096 + t8, &Blds[buf * 16384 + h * 8192 + 4096 + t8]);
    };
    bf16x8 afr[4][2], bfr0[2][2], bfr1[2][2];
    auto DSRA = [&](int buf, int mh) {
#pragma unroll
        for (int mi = 0; mi < 4; ++mi)
#pragma unroll
            for (int ki = 0; ki < 2; ++ki) {
                int rl = wr * 128 + mh * 64 + mi * 16 + l15;
                int g = ki * 4 + lk;
                afr[mi][ki] = *reinterpret_cast<const bf16x8*>(
                    &Alds[buf * 16384 + (rl >> 7) * 8192 + (rl & 127) * 64 + ((g ^ (rl & 7)) << 3)]);
            }
    };
    auto DSRB = [&](int buf, int nh, bf16x8 (&bf)[2][2]) {
#pragma unroll
        for (int nj = 0; nj < 2; ++nj)
#pragma unroll
            for (int ki = 0; ki < 2; ++ki) {
                int rc = wc * 64 + (nh * 2 + nj) * 16 + l15;
                int g = ki * 4 + lk;
                bf[nj][ki] = *reinterpret_cast<const bf16x8*>(
                    &Blds[buf * 16384 + (rc >> 7) * 8192 + (rc & 127) * 64 + ((g ^ (rc & 7)) << 3)]);
            }
    };

    SA(0, 0, 0); SA(0, 1, 0);
    SB(0, 0, 0); SB(0, 1, 0);
    SB(1, 0, 1); SB(1, 1, 1);
    asm volatile("s_waitcnt vmcnt(4)" ::: "memory");
    __builtin_amdgcn_s_barrier();

#pragma unroll 1
    for (int t = 0; t < NT; ++t) {
        const int abuf = t & 1;
        const int bbuf = t % 3;
        const int b3 = (t + 2) % 3;
        DSRA(abuf, 0);
        DSRB(bbuf, 0, bfr0);
        if (t + 1 < NT) { SA(t + 1, 0, abuf ^ 1); SA(t + 1, 1, abuf ^ 1); }
        __builtin_amdgcn_s_barrier();
        __builtin_amdgcn_s_setprio(1);
#pragma unroll
        for (int ki = 0; ki < 2; ++ki)
#pragma unroll
            for (int mi = 0; mi < 4; ++mi)
#pragma unroll
                for (int nj = 0; nj < 2; ++nj)
                    acc[mi][nj] = __builtin_amdgcn_mfma_f32_16x16x32_bf16(afr[mi][ki], bfr0[nj][ki], acc[mi][nj], 0, 0, 0);
        __builtin_amdgcn_s_setprio(0);
        __builtin_amdgcn_s_barrier();
        DSRB(bbuf, 1, bfr1);
        if (t + 2 < NT) SB(t + 2, 0, b3);
        __builtin_amdgcn_s_barrier();
        __builtin_amdgcn_s_setprio(1);
#pragma unroll
        for (int ki = 0; ki < 2; ++ki)
#pragma unroll
            for (int mi = 0; mi < 4; ++mi)
#pragma unroll
                for (int nj = 0; nj < 2; ++nj)
                    acc[mi][2 + nj] = __builtin_amdgcn_mfma_f32_16x16x32_bf16(afr[mi][ki], bfr1[nj][ki], acc[mi][2 + nj], 0, 0, 0);
        __builtin_amdgcn_s_setprio(0);
        __builtin_amdgcn_s_barrier();
        DSRA(abuf, 1);
        if (t + 2 < NT) SB(t + 2, 1, b3);
        __builtin_amdgcn_s_barrier();
        __builtin_amdgcn_s_setprio(1);
#pragma unroll
        for (int ki = 0; ki < 2; ++ki)
#pragma unroll
            for (int mi = 0; mi < 4; ++mi)
#pragma unroll
                for (int nj = 0; nj < 2; ++nj)
                    acc[4 + mi][2 + nj] = __builtin_amdgcn_mfma_f32_16x16x32_bf16(afr[mi][ki], bfr1[nj][ki], acc[4 + mi][2 + nj], 0, 0, 0);
        __builtin_amdgcn_s_setprio(0);
        __builtin_amdgcn_s_barrier();
        __builtin_amdgcn_s_setprio(1);
#pragma unroll
        for (int ki = 0; ki < 2; ++ki)
#pragma unroll
            for (int mi = 0; mi < 4; ++mi)
#pragma unroll
                for (int nj = 0; nj < 2; ++nj)
                    acc[4 + mi][nj] = __builtin_amdgcn_mfma_f32_16x16x32_bf16(afr[mi][ki], bfr0[nj][ki], acc[4 + mi][nj], 0, 0, 0);
        __builtin_amdgcn_s_setprio(0);
        if (t + 2 < NT) { asm volatile("s_waitcnt vmcnt(4)" ::: "memory"); }
        else { asm volatile("s_waitcnt vmcnt(0)" ::: "memory"); }
        __builtin_amdgcn_s_barrier();
    }

#pragma unroll
    for (int mI = 0; mI < 8; ++mI) {
#pragma unroll
        for (int r = 0; r < 4; ++r) {
            int grow = bm * 256 + wr * 128 + mI * 16 + lk * 4 + r;
            if (grow < Mpad) {
#pragma unroll
                for (int nh = 0; nh < 2; ++nh) {
                    float gg = acc[mI][nh * 2 + 0][r];
                    float uu = acc[mI][nh * 2 + 1][r];
                    float h = gg / (1.f + __expf(-gg)) * uu;
                    int n = bn * 256 + wc * 64 + nh * 32 + l15;
                    int jcol = ((n >> 5) << 4) + (n & 15);
                    __bf16 hb = (__bf16)h;
                    ho[toff(hbase + grow, jcol, HKdim)] = __builtin_bit_cast(u16, hb);
                }
            }
        }
    }
}

__device__ __forceinline__ void dev_gemm2(u16* smem, const u16* __restrict__ aBase, const u16* __restrict__ bBase,
                                          u16* __restrict__ yo, int bm, int bn, int M, int rowbase, int AKK, int kt0) {
    u16* Alds = smem;
    u16* Blds = smem + 32768;
    constexpr int NT = 16;
    const u16* aCh[2] = { aBase + (size_t)(2 * bm + 0) * (size_t)(128 * AKK) + (size_t)kt0 * 8192,
                          aBase + (size_t)(2 * bm + 1) * (size_t)(128 * AKK) + (size_t)kt0 * 8192 };
    const u16* bCh[2] = { bBase + (size_t)(2 * bn + 0) * (size_t)(128 * AKK) + (size_t)kt0 * 8192,
                          bBase + (size_t)(2 * bn + 1) * (size_t)(128 * AKK) + (size_t)kt0 * 8192 };
    const int tid = threadIdx.x;
    const int t8 = tid * 8;
    const int lane = tid & 63, wv = tid >> 6;
    const int wr = wv >> 2, wc = wv & 3;
    const int l15 = lane & 15, lk = lane >> 4;

    f32x4 acc[8][4];
#pragma unroll
    for (int m = 0; m < 8; ++m)
#pragma unroll
        for (int n = 0; n < 4; ++n) acc[m][n] = {0.f, 0.f, 0.f, 0.f};

    auto SA = [&](int kt, int h, int buf) {
        glds16(aCh[h] + (size_t)kt * 8192 + t8, &Alds[buf * 16384 + h * 8192 + t8]);
        glds16(aCh[h] + (size_t)kt * 8192 + 4096 + t8, &Alds[buf * 16384 + h * 8192 + 4096 + t8]);
    };
    auto SB = [&](int kt, int h, int buf) {
        glds16(bCh[h] + (size_t)kt * 8192 + t8, &Blds[buf * 16384 + h * 8192 + t8]);
        glds16(bCh[h] + (size_t)kt * 8192 + 4096 + t8, &Blds[buf * 16384 + h * 8192 + 4096 + t8]);
    };
    bf16x8 afr[4][2], bfr0[2][2], bfr1[2][2];
    auto DSRA = [&](int buf, int mh) {
#pragma unroll
        for (int mi = 0; mi < 4; ++mi)
#pragma unroll
            for (int ki = 0; ki < 2; ++ki) {
                int rl = wr * 128 + mh * 64 + mi * 16 + l15;
                int g = ki * 4 + lk;
                afr[mi][ki] = *reinterpret_cast<const bf16x8*>(
                    &Alds[buf * 16384 + (rl >> 7) * 8192 + (rl & 127) * 64 + ((g ^ (rl & 7)) << 3)]);
            }
    };
    auto DSRB = [&](int buf, int nh, bf16x8 (&bf)[2][2]) {
#pragma unroll
        for (int nj = 0; nj < 2; ++nj)
#pragma unroll
            for (int ki = 0; ki < 2; ++ki) {
                int rc = wc * 64 + (nh * 2 + nj) * 16 + l15;
                int g = ki * 4 + lk;
                bf[nj][ki] = *reinterpret_cast<const bf16x8*>(
                    &Blds[buf * 16384 + (rc >> 7) * 8192 + (rc & 127) * 64 + ((g ^ (rc & 7)) << 3)]);
            }
    };

    SA(0, 0, 0); SA(0, 1, 0);
    SB(0, 0, 0); SB(0, 1, 0);
    SB(1, 0, 1); SB(1, 1, 1);
    asm volatile("s_waitcnt vmcnt(4)" ::: "memory");
    __builtin_amdgcn_s_barrier();

#pragma unroll 1
    for (int t = 0; t < NT; ++t) {
        const int abuf = t & 1;
        const int bbuf = t % 3;
        const int b3 = (t + 2) % 3;
        DSRA(abuf, 0);
        DSRB(bbuf, 0, bfr0);
        if (t + 1 < NT) { SA(t + 1, 0, abuf ^ 1); SA(t + 1, 1, abuf ^ 1); }
        __builtin_amdgcn_s_barrier();
        __builtin_amdgcn_s_setprio(1);
#pragma unroll
        for (int ki = 0; ki < 2; ++ki)
#pragma unroll
            for (int mi = 0; mi < 4; ++mi)
#pragma unroll
                for (int nj = 0; nj < 2; ++nj)
                    acc[mi][nj] = __builtin_amdgcn_mfma_f32_16x16x32_bf16(afr[mi][ki], bfr0[nj][ki], acc[mi][nj], 0, 0, 0);
        __builtin_amdgcn_s_setprio(0);
        __builtin_amdgcn_s_barrier();
        DSRB(bbuf, 1, bfr1);
        if (t + 2 < NT) SB(t + 2, 0, b3);
        __builtin_amdgcn_s_barrier();
        __builtin_amdgcn_s_setprio(1);
#pragma unroll
        for (int ki = 0; ki < 2; ++ki)
#pragma unroll
            for (int mi = 0; mi < 4; ++mi)
#pragma unroll
                for (int nj = 0; nj < 2; ++nj)
                    acc[mi][2 + nj] = __builtin_amdgcn_mfma_f32_16x16x32_bf16(afr[mi][ki], bfr1[nj][ki], acc[mi][2 + nj], 0, 0, 0);
        __builtin_amdgcn_s_setprio(0);
        __builtin_amdgcn_s_barrier();
        DSRA(abuf, 1);
        if (t + 2 < NT) SB(t + 2, 1, b3);
        __builtin_amdgcn_s_barrier();
        __builtin_amdgcn_s_setprio(1);
#pragma unroll
        for (int ki = 0; ki < 2; ++ki)
#pragma unroll
            for (int mi = 0; mi < 4; ++mi)
#pragma unroll
                for (int nj = 0; nj < 2; ++nj)
                    acc[4 + mi][2 + nj] = __builtin_amdgcn_mfma_f32_16x16x32_bf16(afr[mi][ki], bfr1[nj][ki], acc[4 + mi][2 + nj], 0, 0, 0);
        __builtin_amdgcn_s_setprio(0);
        __builtin_amdgcn_s_barrier();
        __builtin_amdgcn_s_setprio(1);
#pragma unroll
        for (int ki = 0; ki < 2; ++ki)
#pragma unroll
            for (int mi = 0; mi < 4; ++mi)
#pragma unroll
                for (int nj = 0; nj < 2; ++nj)
                    acc[4 + mi][nj] = __builtin_amdgcn_mfma_f32_16x16x32_bf16(afr[mi][ki], bfr0[nj][ki], acc[4 + mi][nj], 0, 0, 0);
        __builtin_amdgcn_s_setprio(0);
        if (t + 2 < NT) { asm volatile("s_waitcnt vmcnt(4)" ::: "memory"); }
        else { asm volatile("s_waitcnt vmcnt(0)" ::: "memory"); }
        __builtin_amdgcn_s_barrier();
    }

#pragma unroll
    for (int mI = 0; mI < 8; ++mI) {
#pragma unroll
        for (int r = 0; r < 4; ++r) {
            int grow = bm * 256 + wr * 128 + mI * 16 + lk * 4 + r;
            if (grow < M) {
                u16* yr = yo + (size_t)(rowbase + grow) * 2048;
#pragma unroll
                for (int ni = 0; ni < 4; ++ni) {
                    int col = bn * 256 + wc * 64 + ni * 16 + l15;
                    __bf16 yb = (__bf16)acc[mI][ni][r];
                    yr[col] = __builtin_bit_cast(u16, yb);
                }
            }
        }
    }
}

// ---------------- D2': eGEMM1 + sGEMM1 (1/17) + optional wdT transpose tail ----------------
__global__ __launch_bounds__(512, 2) void d2_kernel(const u16* __restrict__ xbT, const u16* __restrict__ WcatE,
                                                    u16* __restrict__ H,
                                                    const u16* __restrict__ WcatS, u16* __restrict__ Hs,
                                                    const float* __restrict__ wd, u16* __restrict__ wdTout,
                                                    const int* __restrict__ counts, const int* __restrict__ poff,
                                                    const int* __restrict__ ids) {
    __shared__ u16 smem[81920];
    int lin = blockIdx.x;
    if (lin < 4352) {
        int t = lin / 17, r = lin % 17;
        if (r == 16) {
            // shared GEMM1 block t (grid 16x16)
            int swz = (t & 7) * 32 + (t >> 3);
            int bm = swz & 15, bn = swz >> 4;
            dev_gemm1(smem, xbT, WcatS, Hs, bm, bn, T_TOK, T_TOK, 0, SINTER, false, 0, nullptr);
        } else {
            int u = t * 16 + r;
            int e = 31 - (((u >> 10) << 3) | (u & 7));
            int j = (u >> 3) & 127;
            int bm = j & 15, bn = j >> 4;
            int M = counts[e];
            if (bm * 256 >= M) return;
            dev_gemm1(smem, xbT, WcatE + (size_t)e * 2048 * DIMK, H,
                      bm, bn, M, (M + 127) & ~127, poff[e], INTERN, true, e, ids);
        }
    } else {
        int u = lin - 4352;
        int e = u >> 9, v = u & 511;
        int kt = v >> 5, jt = v & 31;
        tile_trans_512<false>(wd + (size_t)e * INTERN * DIMK, DIMK, kt * 64, jt * 64,
                              wdTout + (size_t)e * DIMK * INTERN, INTERN, 0, (float*)smem);
    }
}

// ---------------- standalone wdT transpose (fallback when ws too small) ----------------
__global__ __launch_bounds__(512) void wdt_kernel(const float* __restrict__ wd, u16* __restrict__ wdTout) {
    __shared__ float tile[64 * 65];
    int u = blockIdx.x;
    int e = u >> 9, v = u & 511;
    tile_trans_512<false>(wd + (size_t)e * INTERN * DIMK, DIMK, (v >> 5) * 64, (v & 31) * 64,
                          wdTout + (size_t)e * DIMK * INTERN, INTERN, 0, tile);
}

// ---------------- D3': eGEMM2 + sGEMM2 (1/17) ----------------
__global__ __launch_bounds__(512, 2) void d3_kernel(const u16* __restrict__ H, const u16* __restrict__ wdTu,
                                                    u16* __restrict__ Ye,
                                                    const u16* __restrict__ Hs, const u16* __restrict__ swdT,
                                                    u16* __restrict__ Yss,
                                                    const int* __restrict__ counts, const int* __restrict__ poff) {
    __shared__ u16 smem[81920];
    int lin = blockIdx.x;
    int t = lin / 17, r = lin % 17;
    if (r == 16) {
        // shared GEMM2 block t (grid 16x8x2, K-split)
        int swz = (t & 7) * 32 + (t >> 3);
        int bm = swz & 15, bn = (swz >> 4) & 7, ks = swz >> 7;
        dev_gemm2(smem, Hs, swdT, Yss, bm, bn, T_TOK, ks * T_TOK, SINTER, ks * 16);
    } else {
        int u = t * 16 + r;
        int e = 31 - (((u >> 10) << 3) | (u & 7));
        int j = (u >> 3) & 127;
        int bm = j & 15, bn = j >> 4;
        int M = counts[e];
        if (bm * 256 >= M) return;
        dev_gemm2(smem, H + (size_t)poff[e] * INTERN, wdTu + (size_t)e * 2048 * INTERN, Ye,
                  bm, bn, M, poff[e], INTERN, 0);
    }
}

// ---------------- combine: out[t] = Yss0[t] + Yss1[t] + sum_r w_r * Ye[row_r] ----------------
__global__ __launch_bounds__(256) void combine_kernel(const u16* __restrict__ Yss, const u16* __restrict__ Ye,
                                                      const int* __restrict__ tok2row, const float* __restrict__ wtok,
                                                      const int* __restrict__ poff, float* __restrict__ out) {
    const int t = blockIdx.x;
    const int c = threadIdx.x * 8;
    bf16x8 v0 = *reinterpret_cast<const bf16x8*>(Yss + (size_t)t * 2048 + c);
    bf16x8 v1 = *reinterpret_cast<const bf16x8*>(Yss + (size_t)(T_TOK + t) * 2048 + c);
    float acc[8];
#pragma unroll
    for (int j = 0; j < 8; ++j) acc[j] = (float)v0[j] + (float)v1[j];
#pragma unroll
    for (int r = 0; r < NTOPK; ++r) {
        int pk = tok2row[t * NTOPK + r];
        int e = pk >> 12, sl = pk & 4095;
        int row = poff[e] + sl;
        float w = wtok[t * NTOPK + r];
        bf16x8 v = *reinterpret_cast<const bf16x8*>(Ye + (size_t)row * 2048 + c);
#pragma unroll
        for (int j = 0; j < 8; ++j) acc[j] += w * (float)v[j];
    }
    float4 o0 = {acc[0], acc[1], acc[2], acc[3]};
    float4 o1 = {acc[4], acc[5], acc[6], acc[7]};
    float4* po = reinterpret_cast<float4*>(out + (size_t)t * 2048 + c);
    po[0] = o0; po[1] = o1;
}

extern "C" void kernel_launch(void* const* d_in, const int* in_sizes, int n_in,
                              void* d_out, int out_size, void* d_ws, size_t ws_size,
                              hipStream_t stream) {
    const float* x = (const float*)d_in[0];
    const float* gate_w = (const float*)d_in[1];
    const float* wg = (const float*)d_in[2];
    const float* wu = (const float*)d_in[3];
    const float* wd = (const float*)d_in[4];
    const float* swg = (const float*)d_in[5];
    const float* swu = (const float*)d_in[6];
    const float* swd = (const float*)d_in[7];
    float* out = (float*)d_out;

    char* ws = (char*)d_ws;
    size_t off = 0;
    auto alloc = [&](size_t bytes) {
        void* p = ws + off;
        off = (off + bytes + 255) & ~(size_t)255;
        return p;
    };
    u16* xbT = (u16*)alloc((size_t)T_TOK * DIMK * 2);                  // 16.8 MB
    u16* H = (u16*)alloc((size_t)MAXPADROWS * INTERN * 2);             // 59.8 MB
    u16* Hs = (u16*)alloc((size_t)T_TOK * SINTER * 2);                 // 16.8 MB
    u16* Ye = (u16*)alloc((size_t)MAXPADROWS * 2048 * 2);              // 119.6 MB
    u16* Yss = (u16*)alloc((size_t)2 * T_TOK * 2048 * 2);              // 33.6 MB
    int* ids = (int*)alloc((size_t)NEXP * T_TOK * 4);
    int* tok2row = (int*)alloc((size_t)T_TOK * NTOPK * 4);
    float* wtok = (float*)alloc((size_t)T_TOK * NTOPK * 4);
    int* counts = (int*)alloc(NEXP * 4);
    int* poff = (int*)alloc(NEXP * 4);
    u16* WcatS = (u16*)alloc((size_t)(2 * SINTER) * DIMK * 2);         // 16.8 MB
    u16* swdT = (u16*)alloc((size_t)DIMK * SINTER * 2);                // 8.4 MB
    u16* WcatE = (u16*)alloc((size_t)NEXP * (2 * INTERN) * DIMK * 2);  // 268.4 MB
    u16* wdT2 = (u16*)alloc((size_t)NEXP * INTERN * DIMK * 2);         // 134.2 MB (optional)
    const bool wdFused = (off <= ws_size);
    u16* wdTuse = wdFused ? wdT2 : WcatE;  // fallback aliases WcatE (written after D2')

    hipMemsetAsync(counts, 0, NEXP * 4, stream);
    cast_x_tiled_kernel<<<(T_TOK * DIMK) / (256 * 8), 256, 0, stream>>>(x, xbT);
    gate_kernel<<<T_TOK, 64, 0, stream>>>(x, gate_w, counts, ids, tok2row, wtok);
    scan_kernel<<<1, 64, 0, stream>>>(counts, poff);

    // all weight reshapes, one high-occupancy dispatch
    trans_all_kernel<<<35840, 512, 0, stream>>>(swg, swu, swd, wg, wu, WcatS, swdT, WcatE);

    // D2': expert GEMM1 + shared GEMM1 (+ wd transpose tail if ws permits)
    d2_kernel<<<wdFused ? (4352 + 16384) : 4352, 512, 0, stream>>>(
        xbT, WcatE, H, WcatS, Hs, wd, wdTuse, counts, poff, ids);

    if (!wdFused)
        wdt_kernel<<<16384, 512, 0, stream>>>(wd, wdTuse);

    // D3': expert GEMM2 + shared GEMM2
    d3_kernel<<<4352, 512, 0, stream>>>(H, wdTuse, Ye, Hs, swdT, Yss, counts, poff);

    // final combine -> out
    combine_kernel<<<T_TOK, 256, 0, stream>>>(Yss, Ye, tok2row, wtok, poff, out);
}

// Round 18
// 912.746 us; speedup vs baseline: 1.2151x; 1.0397x over previous
//
#include <hip/hip_runtime.h>
#include <hip/hip_bf16.h>

typedef float f32x4 __attribute__((ext_vector_type(4)));
typedef __bf16 bf16x8 __attribute__((ext_vector_type(8)));
typedef unsigned short u16;

#define T_TOK 4096
#define DIMK 2048
#define INTERN 1024
#define NEXP 32
#define NTOPK 6
#define NGRP 8
#define NTOPG 4
#define SINTER 2048
#define MAXPADROWS 29184

__device__ __forceinline__ void glds16(const void* g, void* l) {
    auto* gp = (const __attribute__((address_space(1))) int*)(g);
    auto* lp = (__attribute__((address_space(3))) int*)(l);
    __builtin_amdgcn_global_load_lds(gp, lp, 16, 0, 0);
}

// Chunked+swizzled layout for [Rows][K] bf16: row-chunks 128, k-chunks 64.
// In-chunk (8192 elems): off = row*64 + ((g ^ (row&7))<<3) + (k&7), g=(k>>3)&7.
__device__ __forceinline__ size_t toff(int row, int k, int K) {
    int g = (k >> 3) & 7;
    return (size_t)(row >> 7) * (size_t)(128 * K) + (size_t)(k >> 6) * 8192 +
           (size_t)((row & 127) * 64 + ((g ^ (row & 7)) << 3) + (k & 7));
}

// ---------------- 512-thread 64x64 tile transpose+convert ----------------
template <bool CAT>
__device__ __forceinline__ void tile_trans_512(const float* __restrict__ src, int JD, int k0, int j0,
                                               u16* __restrict__ ob, int KOUT, int s, float* tile) {
    const int tid = threadIdx.x;
    {
        const int r = tid >> 3, c8 = (tid & 7) * 8;
        float4 v0 = *reinterpret_cast<const float4*>(&src[(size_t)(k0 + r) * JD + j0 + c8]);
        float4 v1 = *reinterpret_cast<const float4*>(&src[(size_t)(k0 + r) * JD + j0 + c8 + 4]);
        float* tp = &tile[r * 65 + c8];
        tp[0] = v0.x; tp[1] = v0.y; tp[2] = v0.z; tp[3] = v0.w;
        tp[4] = v1.x; tp[5] = v1.y; tp[6] = v1.z; tp[7] = v1.w;
    }
    __syncthreads();
    {
        const int jl = tid >> 3, kh = (tid & 7) * 8;
        const int j = j0 + jl;
        const int n = CAT ? (((j >> 4) << 5) + s * 16 + (j & 15)) : j;
        bf16x8 o;
#pragma unroll
        for (int jj = 0; jj < 8; ++jj) o[jj] = (__bf16)tile[(kh + jj) * 65 + jl];
        *reinterpret_cast<bf16x8*>(ob + toff(n, k0 + kh, KOUT)) = o;
    }
}

// ---------------- per-wave gate (one token per wave) ----------------
__device__ __forceinline__ void gate_wave(const float* __restrict__ x, const float* __restrict__ gw, int t,
                                          int* __restrict__ counts, int* __restrict__ ids,
                                          int* __restrict__ tok2row, float* __restrict__ wtok,
                                          float* __restrict__ logits) {
    const int lane = threadIdx.x & 63;
    const float4* xr = reinterpret_cast<const float4*>(x + (size_t)t * DIMK);
    for (int e = 0; e < NEXP; ++e) {
        const float4* gr = reinterpret_cast<const float4*>(gw + (size_t)e * DIMK);
        float acc = 0.f;
#pragma unroll
        for (int i = 0; i < DIMK / 4 / 64; ++i) {
            float4 xv = xr[lane + i * 64];
            float4 gv = gr[lane + i * 64];
            acc += xv.x * gv.x + xv.y * gv.y + xv.z * gv.z + xv.w * gv.w;
        }
#pragma unroll
        for (int s = 32; s; s >>= 1) acc += __shfl_xor(acc, s);
        if (lane == 0) logits[e] = acc;
    }
    if (lane != 0) return;
    float sc[NEXP];
#pragma unroll
    for (int e = 0; e < NEXP; ++e) sc[e] = logits[e];
    float mx = sc[0];
#pragma unroll
    for (int e = 1; e < NEXP; ++e) mx = fmaxf(mx, sc[e]);
    float ssum = 0.f;
#pragma unroll
    for (int e = 0; e < NEXP; ++e) { sc[e] = __expf(sc[e] - mx); ssum += sc[e]; }
    const float inv = 1.f / ssum;
    float gsc[NGRP];
#pragma unroll
    for (int g = 0; g < NGRP; ++g) {
        float m2 = sc[g * 4];
#pragma unroll
        for (int j = 1; j < 4; ++j) m2 = fmaxf(m2, sc[g * 4 + j]);
        gsc[g] = m2;
    }
    int gsel = 0;
    for (int r = 0; r < NTOPG; ++r) {
        float bv = -1.f; int bi = 0;
#pragma unroll
        for (int g = 0; g < NGRP; ++g) {
            bool c = (((gsel >> g) & 1) == 0) && (gsc[g] > bv);
            bv = c ? gsc[g] : bv; bi = c ? g : bi;
        }
        gsel |= (1 << bi);
    }
    float msk[NEXP];
#pragma unroll
    for (int e = 0; e < NEXP; ++e) msk[e] = ((gsel >> (e >> 2)) & 1) ? sc[e] : -1.f;
    for (int r = 0; r < NTOPK; ++r) {
        float bv = -3.f; int bi = 0;
#pragma unroll
        for (int e = 0; e < NEXP; ++e) {
            bool c = msk[e] > bv;
            bv = c ? msk[e] : bv; bi = c ? e : bi;
        }
#pragma unroll
        for (int e = 0; e < NEXP; ++e) if (e == bi) msk[e] = -2.f;
        float w = bv * inv;
        int slot = atomicAdd(&counts[bi], 1);
        ids[bi * T_TOK + slot] = t;
        tok2row[t * NTOPK + r] = (bi << 12) | slot;
        wtok[t * NTOPK + r] = w;
    }
}

// ---------------- prep: gate + cast_x + ALL weight reshapes in one dispatch ----------------
// [0,512): gate (8 tok/block); [512,2560): cast; [2560,4608): WcatS; [4608,5632): swdT; [5632,38400): WcatE.
__global__ __launch_bounds__(512) void prep_kernel(
    const float* __restrict__ x, const float* __restrict__ gate_w,
    const float* __restrict__ swg, const float* __restrict__ swu, const float* __restrict__ swd,
    const float* __restrict__ wg, const float* __restrict__ wu,
    u16* __restrict__ xbT, u16* __restrict__ WcatS, u16* __restrict__ swdT, u16* __restrict__ WcatE,
    int* __restrict__ counts, int* __restrict__ ids, int* __restrict__ tok2row, float* __restrict__ wtok) {
    __shared__ float tile[64 * 65];
    int lin = blockIdx.x;
    if (lin < 512) {
        int w = threadIdx.x >> 6;
        gate_wave(x, gate_w, lin * 8 + w, counts, ids, tok2row, wtok, &tile[w * 33]);
    } else if (lin < 2560) {
        int gi = ((lin - 512) * 512 + threadIdx.x) * 8;
        int row = gi >> 11, k = gi & 2047;
        const float4* p = reinterpret_cast<const float4*>(x + gi);
        float4 a = p[0], b = p[1];
        bf16x8 v;
        v[0] = (__bf16)a.x; v[1] = (__bf16)a.y; v[2] = (__bf16)a.z; v[3] = (__bf16)a.w;
        v[4] = (__bf16)b.x; v[5] = (__bf16)b.y; v[6] = (__bf16)b.z; v[7] = (__bf16)b.w;
        *reinterpret_cast<bf16x8*>(xbT + toff(row, k, DIMK)) = v;
    } else if (lin < 4608) {
        int v = lin - 2560;
        int s = v >> 10, u = v & 1023;
        int kt = (u >> 5) & 31, jt = u & 31;
        tile_trans_512<true>((s ? swu : swg), SINTER, kt * 64, jt * 64, WcatS, DIMK, s, tile);
    } else if (lin < 5632) {
        int v = lin - 4608;
        int kt = v >> 5, jt = v & 31;
        tile_trans_512<false>(swd, DIMK, kt * 64, jt * 64, swdT, SINTER, 0, tile);
    } else {
        int u = lin - 5632;
        int e = u >> 10, v = u & 1023;
        int s = (v >> 9) & 1, kt = (v >> 4) & 31, jt = v & 15;
        const float* src = (s ? wu : wg) + (size_t)e * DIMK * INTERN;
        u16* ob = WcatE + (size_t)e * 2048 * DIMK;
        tile_trans_512<true>(src, INTERN, kt * 64, jt * 64, ob, DIMK, s, tile);
    }
}

__global__ void scan_kernel(const int* __restrict__ counts, int* __restrict__ poff) {
    if (threadIdx.x == 0) {
        int o = 0;
        for (int e = 0; e < NEXP; ++e) { poff[e] = o; o += (counts[e] + 127) & ~127; }
    }
}

// ================= r13 GEMM cores as device functions (smem overlay: A=2x16384, B=3x16384 u16) =================
__device__ __forceinline__ void dev_gemm1(u16* smem, const u16* __restrict__ xbT, const u16* __restrict__ b0,
                                          u16* __restrict__ ho, int bm, int bn, int M, int Mpad, int hbase,
                                          int HKdim, bool gath, int e, const int* __restrict__ ids) {
    u16* Alds = smem;
    u16* Blds = smem + 32768;
    constexpr int NT = DIMK / 64;
    const int tid = threadIdx.x;
    const int t8 = tid * 8;
    size_t aSrc[2][2];
#pragma unroll
    for (int h = 0; h < 2; ++h)
#pragma unroll
        for (int j = 0; j < 2; ++j) {
            int drow = j * 64 + (tid >> 3);
            int row = bm * 256 + h * 128 + drow;
            int tok;
            if (gath) { int cr = row < M ? row : M - 1; tok = ids[e * T_TOK + cr]; }
            else tok = row;
            int slot = (tid & 7) ^ (drow & 7) ^ (tok & 7);
            aSrc[h][j] = (size_t)(tok >> 7) * (size_t)(128 * 2048) + (size_t)((tok & 127) * 64 + slot * 8);
        }
    const u16* bCh[2] = { b0 + (size_t)(2 * bn + 0) * (128 * 2048), b0 + (size_t)(2 * bn + 1) * (128 * 2048) };

    const int lane = tid & 63, wv = tid >> 6;
    const int wr = wv >> 2, wc = wv & 3;
    const int l15 = lane & 15, lk = lane >> 4;

    f32x4 acc[8][4];
#pragma unroll
    for (int m = 0; m < 8; ++m)
#pragma unroll
        for (int n = 0; n < 4; ++n) acc[m][n] = {0.f, 0.f, 0.f, 0.f};

    auto SA = [&](int kt, int h, int buf) {
        glds16(xbT + aSrc[h][0] + (size_t)kt * 8192, &Alds[buf * 16384 + h * 8192 + t8]);
        glds16(xbT + aSrc[h][1] + (size_t)kt * 8192, &Alds[buf * 16384 + h * 8192 + 4096 + t8]);
    };
    auto SB = [&](int kt, int h, int buf) {
        glds16(bCh[h] + (size_t)kt * 8192 + t8, &Blds[buf * 16384 + h * 8192 + t8]);
        glds16(bCh[h] + (size_t)kt * 8192 + 4096 + t8, &Blds[buf * 16384 + h * 8192 + 4096 + t8]);
    };
    bf16x8 afr[4][2], bfr0[2][2], bfr1[2][2];
    auto DSRA = [&](int buf, int mh) {
#pragma unroll
        for (int mi = 0; mi < 4; ++mi)
#pragma unroll
            for (int ki = 0; ki < 2; ++ki) {
                int rl = wr * 128 + mh * 64 + mi * 16 + l15;
                int g = ki * 4 + lk;
                afr[mi][ki] = *reinterpret_cast<const bf16x8*>(
                    &Alds[buf * 16384 + (rl >> 7) * 8192 + (rl & 127) * 64 + ((g ^ (rl & 7)) << 3)]);
            }
    };
    auto DSRB = [&](int buf, int nh, bf16x8 (&bf)[2][2]) {
#pragma unroll
        for (int nj = 0; nj < 2; ++nj)
#pragma unroll
            for (int ki = 0; ki < 2; ++ki) {
                int rc = wc * 64 + (nh * 2 + nj) * 16 + l15;
                int g = ki * 4 + lk;
                bf[nj][ki] = *reinterpret_cast<const bf16x8*>(
                    &Blds[buf * 16384 + (rc >> 7) * 8192 + (rc & 127) * 64 + ((g ^ (rc & 7)) << 3)]);
            }
    };

    SA(0, 0, 0); SA(0, 1, 0);
    SB(0, 0, 0); SB(0, 1, 0);
    SB(1, 0, 1); SB(1, 1, 1);
    asm volatile("s_waitcnt vmcnt(4)" ::: "memory");
    __builtin_amdgcn_s_barrier();

#pragma unroll 1
    for (int t = 0; t < NT; ++t) {
        const int abuf = t & 1;
        const int bbuf = t % 3;
        const int b3 = (t + 2) % 3;
        DSRA(abuf, 0);
        DSRB(bbuf, 0, bfr0);
        if (t + 1 < NT) { SA(t + 1, 0, abuf ^ 1); SA(t + 1, 1, abuf ^ 1); }
        __builtin_amdgcn_s_barrier();
        __builtin_amdgcn_s_setprio(1);
#pragma unroll
        for (int ki = 0; ki < 2; ++ki)
#pragma unroll
            for (int mi = 0; mi < 4; ++mi)
#pragma unroll
                for (int nj = 0; nj < 2; ++nj)
                    acc[mi][nj] = __builtin_amdgcn_mfma_f32_16x16x32_bf16(afr[mi][ki], bfr0[nj][ki], acc[mi][nj], 0, 0, 0);
        __builtin_amdgcn_s_setprio(0);
        __builtin_amdgcn_s_barrier();
        DSRB(bbuf, 1, bfr1);
        if (t + 2 < NT) SB(t + 2, 0, b3);
        __builtin_amdgcn_s_barrier();
        __builtin_amdgcn_s_setprio(1);
#pragma unroll
        for (int ki = 0; ki < 2; ++ki)
#pragma unroll
            for (int mi = 0; mi < 4; ++mi)
#pragma unroll
                for (int nj = 0; nj < 2; ++nj)
                    acc[mi][2 + nj] = __builtin_amdgcn_mfma_f32_16x16x32_bf16(afr[mi][ki], bfr1[nj][ki], acc[mi][2 + nj], 0, 0, 0);
        __builtin_amdgcn_s_setprio(0);
        __builtin_amdgcn_s_barrier();
        DSRA(abuf, 1);
        if (t + 2 < NT) SB(t + 2, 1, b3);
        __builtin_amdgcn_s_barrier();
        __builtin_amdgcn_s_setprio(1);
#pragma unroll
        for (int ki = 0; ki < 2; ++ki)
#pragma unroll
            for (int mi = 0; mi < 4; ++mi)
#pragma unroll
                for (int nj = 0; nj < 2; ++nj)
                    acc[4 + mi][2 + nj] = __builtin_amdgcn_mfma_f32_16x16x32_bf16(afr[mi][ki], bfr1[nj][ki], acc[4 + mi][2 + nj], 0, 0, 0);
        __builtin_amdgcn_s_setprio(0);
        __builtin_amdgcn_s_barrier();
        __builtin_amdgcn_s_setprio(1);
#pragma unroll
        for (int ki = 0; ki < 2; ++ki)
#pragma unroll
            for (int mi = 0; mi < 4; ++mi)
#pragma unroll
                for (int nj = 0; nj < 2; ++nj)
                    acc[4 + mi][nj] = __builtin_amdgcn_mfma_f32_16x16x32_bf16(afr[mi][ki], bfr0[nj][ki], acc[4 + mi][nj], 0, 0, 0);
        __builtin_amdgcn_s_setprio(0);
        if (t + 2 < NT) { asm volatile("s_waitcnt vmcnt(4)" ::: "memory"); }
        else { asm volatile("s_waitcnt vmcnt(0)" ::: "memory"); }
        __builtin_amdgcn_s_barrier();
    }

#pragma unroll
    for (int mI = 0; mI < 8; ++mI) {
#pragma unroll
        for (int r = 0; r < 4; ++r) {
            int grow = bm * 256 + wr * 128 + mI * 16 + lk * 4 + r;
            if (grow < Mpad) {
#pragma unroll
                for (int nh = 0; nh < 2; ++nh) {
                    float gg = acc[mI][nh * 2 + 0][r];
                    float uu = acc[mI][nh * 2 + 1][r];
                    float h = gg / (1.f + __expf(-gg)) * uu;
                    int n = bn * 256 + wc * 64 + nh * 32 + l15;
                    int jcol = ((n >> 5) << 4) + (n & 15);
                    __bf16 hb = (__bf16)h;
                    ho[toff(hbase + grow, jcol, HKdim)] = __builtin_bit_cast(u16, hb);
                }
            }
        }
    }
}

__device__ __forceinline__ void dev_gemm2(u16* smem, const u16* __restrict__ aBase, const u16* __restrict__ bBase,
                                          u16* __restrict__ yo, int bm, int bn, int M, int rowbase, int AKK, int kt0) {
    u16* Alds = smem;
    u16* Blds = smem + 32768;
    constexpr int NT = 16;
    const u16* aCh[2] = { aBase + (size_t)(2 * bm + 0) * (size_t)(128 * AKK) + (size_t)kt0 * 8192,
                          aBase + (size_t)(2 * bm + 1) * (size_t)(128 * AKK) + (size_t)kt0 * 8192 };
    const u16* bCh[2] = { bBase + (size_t)(2 * bn + 0) * (size_t)(128 * AKK) + (size_t)kt0 * 8192,
                          bBase + (size_t)(2 * bn + 1) * (size_t)(128 * AKK) + (size_t)kt0 * 8192 };
    const int tid = threadIdx.x;
    const int t8 = tid * 8;
    const int lane = tid & 63, wv = tid >> 6;
    const int wr = wv >> 2, wc = wv & 3;
    const int l15 = lane & 15, lk = lane >> 4;

    f32x4 acc[8][4];
#pragma unroll
    for (int m = 0; m < 8; ++m)
#pragma unroll
        for (int n = 0; n < 4; ++n) acc[m][n] = {0.f, 0.f, 0.f, 0.f};

    auto SA = [&](int kt, int h, int buf) {
        glds16(aCh[h] + (size_t)kt * 8192 + t8, &Alds[buf * 16384 + h * 8192 + t8]);
        glds16(aCh[h] + (size_t)kt * 8192 + 4096 + t8, &Alds[buf * 16384 + h * 8192 + 4096 + t8]);
    };
    auto SB = [&](int kt, int h, int buf) {
        glds16(bCh[h] + (size_t)kt * 8192 + t8, &Blds[buf * 16384 + h * 8192 + t8]);
        glds16(bCh[h] + (size_t)kt * 8192 + 4096 + t8, &Blds[buf * 16384 + h * 8192 + 4096 + t8]);
    };
    bf16x8 afr[4][2], bfr0[2][2], bfr1[2][2];
    auto DSRA = [&](int buf, int mh) {
#pragma unroll
        for (int mi = 0; mi < 4; ++mi)
#pragma unroll
            for (int ki = 0; ki < 2; ++ki) {
                int rl = wr * 128 + mh * 64 + mi * 16 + l15;
                int g = ki * 4 + lk;
                afr[mi][ki] = *reinterpret_cast<const bf16x8*>(
                    &Alds[buf * 16384 + (rl >> 7) * 8192 + (rl & 127) * 64 + ((g ^ (rl & 7)) << 3)]);
            }
    };
    auto DSRB = [&](int buf, int nh, bf16x8 (&bf)[2][2]) {
#pragma unroll
        for (int nj = 0; nj < 2; ++nj)
#pragma unroll
            for (int ki = 0; ki < 2; ++ki) {
                int rc = wc * 64 + (nh * 2 + nj) * 16 + l15;
                int g = ki * 4 + lk;
                bf[nj][ki] = *reinterpret_cast<const bf16x8*>(
                    &Blds[buf * 16384 + (rc >> 7) * 8192 + (rc & 127) * 64 + ((g ^ (rc & 7)) << 3)]);
            }
    };

    SA(0, 0, 0); SA(0, 1, 0);
    SB(0, 0, 0); SB(0, 1, 0);
    SB(1, 0, 1); SB(1, 1, 1);
    asm volatile("s_waitcnt vmcnt(4)" ::: "memory");
    __builtin_amdgcn_s_barrier();

#pragma unroll 1
    for (int t = 0; t < NT; ++t) {
        const int abuf = t & 1;
        const int bbuf = t % 3;
        const int b3 = (t + 2) % 3;
        DSRA(abuf, 0);
        DSRB(bbuf, 0, bfr0);
        if (t + 1 < NT) { SA(t + 1, 0, abuf ^ 1); SA(t + 1, 1, abuf ^ 1); }
        __builtin_amdgcn_s_barrier();
        __builtin_amdgcn_s_setprio(1);
#pragma unroll
        for (int ki = 0; ki < 2; ++ki)
#pragma unroll
            for (int mi = 0; mi < 4; ++mi)
#pragma unroll
                for (int nj = 0; nj < 2; ++nj)
                    acc[mi][nj] = __builtin_amdgcn_mfma_f32_16x16x32_bf16(afr[mi][ki], bfr0[nj][ki], acc[mi][nj], 0, 0, 0);
        __builtin_amdgcn_s_setprio(0);
        __builtin_amdgcn_s_barrier();
        DSRB(bbuf, 1, bfr1);
        if (t + 2 < NT) SB(t + 2, 0, b3);
        __builtin_amdgcn_s_barrier();
        __builtin_amdgcn_s_setprio(1);
#pragma unroll
        for (int ki = 0; ki < 2; ++ki)
#pragma unroll
            for (int mi = 0; mi < 4; ++mi)
#pragma unroll
                for (int nj = 0; nj < 2; ++nj)
                    acc[mi][2 + nj] = __builtin_amdgcn_mfma_f32_16x16x32_bf16(afr[mi][ki], bfr1[nj][ki], acc[mi][2 + nj], 0, 0, 0);
        __builtin_amdgcn_s_setprio(0);
        __builtin_amdgcn_s_barrier();
        DSRA(abuf, 1);
        if (t + 2 < NT) SB(t + 2, 1, b3);
        __builtin_amdgcn_s_barrier();
        __builtin_amdgcn_s_setprio(1);
#pragma unroll
        for (int ki = 0; ki < 2; ++ki)
#pragma unroll
            for (int mi = 0; mi < 4; ++mi)
#pragma unroll
                for (int nj = 0; nj < 2; ++nj)
                    acc[4 + mi][2 + nj] = __builtin_amdgcn_mfma_f32_16x16x32_bf16(afr[mi][ki], bfr1[nj][ki], acc[4 + mi][2 + nj], 0, 0, 0);
        __builtin_amdgcn_s_setprio(0);
        __builtin_amdgcn_s_barrier();
        __builtin_amdgcn_s_setprio(1);
#pragma unroll
        for (int ki = 0; ki < 2; ++ki)
#pragma unroll
            for (int mi = 0; mi < 4; ++mi)
#pragma unroll
                for (int nj = 0; nj < 2; ++nj)
                    acc[4 + mi][nj] = __builtin_amdgcn_mfma_f32_16x16x32_bf16(afr[mi][ki], bfr0[nj][ki], acc[4 + mi][nj], 0, 0, 0);
        __builtin_amdgcn_s_setprio(0);
        if (t + 2 < NT) { asm volatile("s_waitcnt vmcnt(4)" ::: "memory"); }
        else { asm volatile("s_waitcnt vmcnt(0)" ::: "memory"); }
        __builtin_amdgcn_s_barrier();
    }

#pragma unroll
    for (int mI = 0; mI < 8; ++mI) {
#pragma unroll
        for (int r = 0; r < 4; ++r) {
            int grow = bm * 256 + wr * 128 + mI * 16 + lk * 4 + r;
            if (grow < M) {
                u16* yr = yo + (size_t)(rowbase + grow) * 2048;
#pragma unroll
                for (int ni = 0; ni < 4; ++ni) {
                    int col = bn * 256 + wc * 64 + ni * 16 + l15;
                    __bf16 yb = (__bf16)acc[mI][ni][r];
                    yr[col] = __builtin_bit_cast(u16, yb);
                }
            }
        }
    }
}

// ---------------- D2': eGEMM1 + sGEMM1 (1/17) + optional wdT transpose tail ----------------
__global__ __launch_bounds__(512, 2) void d2_kernel(const u16* __restrict__ xbT, const u16* __restrict__ WcatE,
                                                    u16* __restrict__ H,
                                                    const u16* __restrict__ WcatS, u16* __restrict__ Hs,
                                                    const float* __restrict__ wd, u16* __restrict__ wdTout,
                                                    const int* __restrict__ counts, const int* __restrict__ poff,
                                                    const int* __restrict__ ids) {
    __shared__ u16 smem[81920];
    int lin = blockIdx.x;
    if (lin < 4352) {
        int t = lin / 17, r = lin % 17;
        if (r == 16) {
            int swz = (t & 7) * 32 + (t >> 3);
            int bm = swz & 15, bn = swz >> 4;
            dev_gemm1(smem, xbT, WcatS, Hs, bm, bn, T_TOK, T_TOK, 0, SINTER, false, 0, nullptr);
        } else {
            int u = t * 16 + r;
            int e = 31 - (((u >> 10) << 3) | (u & 7));
            int j = (u >> 3) & 127;
            int bm = j & 15, bn = j >> 4;
            int M = counts[e];
            if (bm * 256 >= M) return;
            dev_gemm1(smem, xbT, WcatE + (size_t)e * 2048 * DIMK, H,
                      bm, bn, M, (M + 127) & ~127, poff[e], INTERN, true, e, ids);
        }
    } else {
        int u = lin - 4352;
        int e = u >> 9, v = u & 511;
        int kt = v >> 5, jt = v & 31;
        tile_trans_512<false>(wd + (size_t)e * INTERN * DIMK, DIMK, kt * 64, jt * 64,
                              wdTout + (size_t)e * DIMK * INTERN, INTERN, 0, (float*)smem);
    }
}

// ---------------- standalone wdT transpose (fallback when ws too small) ----------------
__global__ __launch_bounds__(512) void wdt_kernel(const float* __restrict__ wd, u16* __restrict__ wdTout) {
    __shared__ float tile[64 * 65];
    int u = blockIdx.x;
    int e = u >> 9, v = u & 511;
    tile_trans_512<false>(wd + (size_t)e * INTERN * DIMK, DIMK, (v >> 5) * 64, (v & 31) * 64,
                          wdTout + (size_t)e * DIMK * INTERN, INTERN, 0, tile);
}

// ---------------- D3': eGEMM2 + sGEMM2 (1/17) ----------------
__global__ __launch_bounds__(512, 2) void d3_kernel(const u16* __restrict__ H, const u16* __restrict__ wdTu,
                                                    u16* __restrict__ Ye,
                                                    const u16* __restrict__ Hs, const u16* __restrict__ swdT,
                                                    u16* __restrict__ Yss,
                                                    const int* __restrict__ counts, const int* __restrict__ poff) {
    __shared__ u16 smem[81920];
    int lin = blockIdx.x;
    int t = lin / 17, r = lin % 17;
    if (r == 16) {
        int swz = (t & 7) * 32 + (t >> 3);
        int bm = swz & 15, bn = (swz >> 4) & 7, ks = swz >> 7;
        dev_gemm2(smem, Hs, swdT, Yss, bm, bn, T_TOK, ks * T_TOK, SINTER, ks * 16);
    } else {
        int u = t * 16 + r;
        int e = 31 - (((u >> 10) << 3) | (u & 7));
        int j = (u >> 3) & 127;
        int bm = j & 15, bn = j >> 4;
        int M = counts[e];
        if (bm * 256 >= M) return;
        dev_gemm2(smem, H + (size_t)poff[e] * INTERN, wdTu + (size_t)e * 2048 * INTERN, Ye,
                  bm, bn, M, poff[e], INTERN, 0);
    }
}

// ---------------- combine: out[t] = Yss0[t] + Yss1[t] + sum_r w_r * Ye[row_r] ----------------
__global__ __launch_bounds__(256) void combine_kernel(const u16* __restrict__ Yss, const u16* __restrict__ Ye,
                                                      const int* __restrict__ tok2row, const float* __restrict__ wtok,
                                                      const int* __restrict__ poff, float* __restrict__ out) {
    const int t = blockIdx.x;
    const int c = threadIdx.x * 8;
    bf16x8 v0 = *reinterpret_cast<const bf16x8*>(Yss + (size_t)t * 2048 + c);
    bf16x8 v1 = *reinterpret_cast<const bf16x8*>(Yss + (size_t)(T_TOK + t) * 2048 + c);
    float acc[8];
#pragma unroll
    for (int j = 0; j < 8; ++j) acc[j] = (float)v0[j] + (float)v1[j];
#pragma unroll
    for (int r = 0; r < NTOPK; ++r) {
        int pk = tok2row[t * NTOPK + r];
        int e = pk >> 12, sl = pk & 4095;
        int row = poff[e] + sl;
        float w = wtok[t * NTOPK + r];
        bf16x8 v = *reinterpret_cast<const bf16x8*>(Ye + (size_t)row * 2048 + c);
#pragma unroll
        for (int j = 0; j < 8; ++j) acc[j] += w * (float)v[j];
    }
    float4 o0 = {acc[0], acc[1], acc[2], acc[3]};
    float4 o1 = {acc[4], acc[5], acc[6], acc[7]};
    float4* po = reinterpret_cast<float4*>(out + (size_t)t * 2048 + c);
    po[0] = o0; po[1] = o1;
}

extern "C" void kernel_launch(void* const* d_in, const int* in_sizes, int n_in,
                              void* d_out, int out_size, void* d_ws, size_t ws_size,
                              hipStream_t stream) {
    const float* x = (const float*)d_in[0];
    const float* gate_w = (const float*)d_in[1];
    const float* wg = (const float*)d_in[2];
    const float* wu = (const float*)d_in[3];
    const float* wd = (const float*)d_in[4];
    const float* swg = (const float*)d_in[5];
    const float* swu = (const float*)d_in[6];
    const float* swd = (const float*)d_in[7];
    float* out = (float*)d_out;

    char* ws = (char*)d_ws;
    size_t off = 0;
    auto alloc = [&](size_t bytes) {
        void* p = ws + off;
        off = (off + bytes + 255) & ~(size_t)255;
        return p;
    };
    u16* xbT = (u16*)alloc((size_t)T_TOK * DIMK * 2);                  // 16.8 MB
    u16* H = (u16*)alloc((size_t)MAXPADROWS * INTERN * 2);             // 59.8 MB
    u16* Hs = (u16*)alloc((size_t)T_TOK * SINTER * 2);                 // 16.8 MB
    u16* Ye = (u16*)alloc((size_t)MAXPADROWS * 2048 * 2);              // 119.6 MB
    u16* Yss = (u16*)alloc((size_t)2 * T_TOK * 2048 * 2);              // 33.6 MB
    int* ids = (int*)alloc((size_t)NEXP * T_TOK * 4);
    int* tok2row = (int*)alloc((size_t)T_TOK * NTOPK * 4);
    float* wtok = (float*)alloc((size_t)T_TOK * NTOPK * 4);
    int* counts = (int*)alloc(NEXP * 4);
    int* poff = (int*)alloc(NEXP * 4);
    u16* WcatS = (u16*)alloc((size_t)(2 * SINTER) * DIMK * 2);         // 16.8 MB
    u16* swdT = (u16*)alloc((size_t)DIMK * SINTER * 2);                // 8.4 MB
    u16* WcatE = (u16*)alloc((size_t)NEXP * (2 * INTERN) * DIMK * 2);  // 268.4 MB
    u16* wdT2 = (u16*)alloc((size_t)NEXP * INTERN * DIMK * 2);         // 134.2 MB (optional)
    const bool wdFused = (off <= ws_size);
    u16* wdTuse = wdFused ? wdT2 : WcatE;  // fallback aliases WcatE (written after D2')

    hipMemsetAsync(counts, 0, NEXP * 4, stream);

    // prep: gate + cast + all weight reshapes, one dispatch
    prep_kernel<<<38400, 512, 0, stream>>>(x, gate_w, swg, swu, swd, wg, wu,
                                           xbT, WcatS, swdT, WcatE, counts, ids, tok2row, wtok);
    scan_kernel<<<1, 64, 0, stream>>>(counts, poff);

    // D2': expert GEMM1 + shared GEMM1 (+ wd transpose tail if ws permits)
    d2_kernel<<<wdFused ? (4352 + 16384) : 4352, 512, 0, stream>>>(
        xbT, WcatE, H, WcatS, Hs, wd, wdTuse, counts, poff, ids);

    if (!wdFused)
        wdt_kernel<<<16384, 512, 0, stream>>>(wd, wdTuse);

    // D3': expert GEMM2 + shared GEMM2
    d3_kernel<<<4352, 512, 0, stream>>>(H, wdTuse, Ye, Hs, swdT, Yss, counts, poff);

    // final combine -> out
    combine_kernel<<<T_TOK, 256, 0, stream>>>(Yss, Ye, tok2row, wtok, poff, out);
}